// Round 5
// baseline (413.673 us; speedup 1.0000x reference)
//
#include <hip/hip_runtime.h>
#include <math.h>

typedef __attribute__((ext_vector_type(8))) short short8;
typedef __attribute__((ext_vector_type(4))) float f32x4;
typedef __attribute__((ext_vector_type(4))) unsigned int u32x4;

union U8 { unsigned int u[4]; short8 s; u32x4 v; };

// ---------------- helpers ----------------

__device__ __forceinline__ float wave_sum(float v) {
#pragma unroll
    for (int o = 32; o > 0; o >>= 1) v += __shfl_down(v, o);
    return v;
}

__device__ __forceinline__ float block_sum256(float v, float* red) {
    v = wave_sum(v);
    int t = threadIdx.x;
    if ((t & 63) == 0) red[t >> 6] = v;
    __syncthreads();
    float r = red[0] + red[1] + red[2] + red[3];
    __syncthreads();
    return r;
}

__device__ __forceinline__ unsigned fenc(float f) {
    unsigned u = __float_as_uint(f);
    return (u & 0x80000000u) ? ~u : (u | 0x80000000u);
}
__device__ __forceinline__ float fdec(unsigned u) {
    return (u & 0x80000000u) ? __uint_as_float(u & 0x7fffffffu) : __uint_as_float(~u);
}

__device__ __forceinline__ ushort f2bf(float f) {
    unsigned u = __float_as_uint(f);
    unsigned r = (u + 0x7fffu + ((u >> 16) & 1u)) >> 16;
    return (ushort)r;
}
__device__ __forceinline__ float bflo(unsigned u) { return __uint_as_float(u << 16); }
__device__ __forceinline__ float bfhi(unsigned u) { return __uint_as_float(u & 0xffff0000u); }
__device__ __forceinline__ float bf2f(ushort u) { return __uint_as_float((unsigned)u << 16); }

// ---------------- ws float layout ----------------
// 0..527 scalars + hists (ints)
// 528 rnorm[512] -> 1040
// 1040 A1bf (65536 bf16) -> 33808
// 33808 A2bf (65536 bf16) -> 66576
// 66576 ebf (131072 bf16) -> 132112
// 132112 Ebf (65536 bf16) -> 164880
// 164880 W3cpk (65536 bf16) -> 197648
// 197648 W4pk (32768 bf16) -> 214032
// 214032 W1pk (131072 bf16) -> 279568
// 279568 W2pk (65536 bf16) -> 312336
// 312336 W3apk (65536 bf16) -> 345104
// 345104 W3bpk (65536 bf16) -> 377872
// 377872 fT fp32[262144] -> 640016
// 640016 top5 int[2560] -> 642576

__global__ void init_kernel(float* wsf, unsigned* wsu, int* wsi) {
    int t = threadIdx.x;
    if (t < 7) wsf[t] = 0.f;
    if (t == 7 || t == 9) wsu[t] = 0xFFFFFFFFu;
    if (t == 8 || t == 10) wsu[t] = 0u;
    wsi[16 + t] = 0;
    wsi[272 + t] = 0;
}

// pack a [K x 256] fp32 matrix into bf16 A-fragment order; s indexes slots.
__device__ __forceinline__ void pack256(const float* __restrict__ src, ushort* __restrict__ dst, int s) {
    int lane = s & 63;
    int tt = (s >> 6) & 15;
    int kk = s >> 10;
    int qq = lane >> 4, nn = lane & 15;
    int tcol = tt * 16 + nn;
    short8 v;
#pragma unroll
    for (int jj = 0; jj < 8; ++jj) {
        int k = kk * 32 + qq * 8 + jj;
        v[jj] = (short)f2bf(src[(size_t)k * 256 + tcol]);
    }
    *(short8*)(dst + (size_t)s * 8) = v;
}

// pack a [256 x 128] fp32 matrix into bf16 A-fragment order (8 tt).
__device__ __forceinline__ void pack128(const float* __restrict__ src, ushort* __restrict__ dst, int s) {
    int lane = s & 63;
    int tt = (s >> 6) & 7;
    int kk = s >> 9;
    int qq = lane >> 4, nn = lane & 15;
    int ncol = tt * 16 + nn;
    short8 v;
#pragma unroll
    for (int jj = 0; jj < 8; ++jj) {
        int k = kk * 32 + qq * 8 + jj;
        v[jj] = (short)f2bf(src[(size_t)k * 128 + ncol]);
    }
    *(short8*)(dst + (size_t)s * 8) = v;
}

// ---------------- mega: stats + transpose + packs ----------------
__global__ __launch_bounds__(256) void mega_kernel(
    const float4* __restrict__ o, const float4* __restrict__ im,
    const float4* __restrict__ cf1, const float4* __restrict__ cf2,
    const float* __restrict__ fo, const float* __restrict__ fr,
    const float* __restrict__ W1, const float* __restrict__ W2,
    const float* __restrict__ W3, const float* __restrict__ W4,
    float* wsf, unsigned* wsu, float* rnorm, float* fT,
    ushort* __restrict__ W3cpk, ushort* __restrict__ W4pk,
    ushort* __restrict__ W1pk, ushort* __restrict__ W2pk,
    ushort* __restrict__ W3apk, ushort* __restrict__ W3bpk) {
    __shared__ float smem[64 * 33];
    float* red = smem;
    int b = blockIdx.x, t = threadIdx.x;
    if (b < 2048) {
        if (b < 512) {
            float s = 0.f;
            for (int i = b * 256 + t; i < 786432; i += 512 * 256) {
                float4 a = o[i], c = im[i];
                float dx = a.x - c.x, dy = a.y - c.y, dz = a.z - c.z, dw = a.w - c.w;
                s += dx * dx + dy * dy + dz * dz + dw * dw;
            }
            float tot = block_sum256(s, red);
            if (t == 0) atomicAdd(wsf + 0, tot);
        } else if (b < 1536) {
            int which = (b < 1024) ? 0 : 1;
            const float4* x = which ? cf2 : cf1;
            int n4 = which ? 524288 : 1048576;
            int b0 = which ? 1024 : 512;
            float s = 0.f, mn = INFINITY, mx = -INFINITY;
            for (int i = (b - b0) * 256 + t; i < n4; i += 512 * 256) {
                float4 a = x[i];
                s += fabsf(a.x) + fabsf(a.y) + fabsf(a.z) + fabsf(a.w);
                mn = fminf(mn, fminf(fminf(a.x, a.y), fminf(a.z, a.w)));
                mx = fmaxf(mx, fmaxf(fmaxf(a.x, a.y), fmaxf(a.z, a.w)));
            }
            float tot = block_sum256(s, red);
#pragma unroll
            for (int off = 32; off > 0; off >>= 1) {
                mn = fminf(mn, __shfl_down(mn, off));
                mx = fmaxf(mx, __shfl_down(mx, off));
            }
            float* rmn = smem + 8;
            float* rmx = smem + 16;
            if ((t & 63) == 0) { rmn[t >> 6] = mn; rmx[t >> 6] = mx; }
            __syncthreads();
            if (t == 0) {
                atomicAdd(wsf + 1 + which, tot);
                float m1 = fminf(fminf(rmn[0], rmn[1]), fminf(rmn[2], rmn[3]));
                float m2 = fmaxf(fmaxf(rmx[0], rmx[1]), fmaxf(rmx[2], rmx[3]));
                atomicMin(wsu + 7 + which * 2, fenc(m1));
                atomicMax(wsu + 8 + which * 2, fenc(m2));
            }
        } else {
            int r = b - 1536;
            const float4* f = (r < 256) ? ((const float4*)fo + (size_t)r * 128)
                                        : ((const float4*)fr + (size_t)(r - 256) * 128);
            float s = 0.f;
            if (t < 128) {
                float4 a = f[t];
                s = a.x * a.x + a.y * a.y + a.z * a.z + a.w * a.w;
            }
            float tot = block_sum256(s, red);
            if (t == 0) rnorm[r] = 1.0f / sqrtf(tot);
        }
    } else if (b < 2176) {
        // transpose: fT[pass][k][j] = f[j][k]
        int bb = b - 2048;
        int pass = bb >> 6;
        int kt = (bb >> 2) & 15;
        int jt = bb & 3;
        int k0 = kt * 32, j0 = jt * 64;
        const float* f = pass ? fr : fo;
        float (*tile)[33] = (float(*)[33])smem;
        int cl = t & 31, rl = t >> 5;
#pragma unroll
        for (int r = 0; r < 8; ++r) {
            int row = j0 + rl + r * 8;
            tile[rl + r * 8][cl] = f[(size_t)row * 512 + k0 + cl];
        }
        __syncthreads();
        int jl = t & 63, kq = t >> 6;
        float* dst = fT + (size_t)pass * 131072;
#pragma unroll
        for (int c = 0; c < 8; ++c) {
            int kl = kq * 8 + c;
            dst[(size_t)(k0 + kl) * 256 + j0 + jl] = tile[jl][kl];
        }
    } else {
        int pb = b - 2176;
        if (pb < 32) pack256(W3 + 512 * 256, W3cpk, pb * 256 + t);
        else if (pb < 48) pack128(W4, W4pk, (pb - 32) * 256 + t);
        else if (pb < 112) pack256(W1, W1pk, (pb - 48) * 256 + t);
        else if (pb < 144) pack256(W2, W2pk, (pb - 112) * 256 + t);
        else if (pb < 176) pack256(W3, W3apk, (pb - 144) * 256 + t);
        else pack256(W3 + 256 * 256, W3bpk, (pb - 176) * 256 + t);
    }
}

// ---------------- merged histogram ----------------
__global__ __launch_bounds__(256) void hist_kernel(const float4* __restrict__ cf1,
                                                   const float4* __restrict__ cf2,
                                                   const unsigned* wsu, int* wsi) {
    __shared__ int hl[256];
    int b = blockIdx.x, t = threadIdx.x;
    hl[t] = 0;
    __syncthreads();
    int which = (b < 512) ? 0 : 1;
    const float4* x = which ? cf2 : cf1;
    int n4 = which ? 524288 : 1048576;
    int b0 = which ? 512 : 0;
    int* hist = wsi + (which ? 272 : 16);
    float mn = fdec(wsu[7 + which * 2]), mx = fdec(wsu[8 + which * 2]);
    float inv = 256.f / (mx - mn + 1e-8f);
    for (int i = (b - b0) * 256 + t; i < n4; i += 512 * 256) {
        float4 a = x[i];
        int b0i = min(max((int)floorf((a.x - mn) * inv), 0), 255);
        int b1i = min(max((int)floorf((a.y - mn) * inv), 0), 255);
        int b2i = min(max((int)floorf((a.z - mn) * inv), 0), 255);
        int b3i = min(max((int)floorf((a.w - mn) * inv), 0), 255);
        atomicAdd(&hl[b0i], 1);
        atomicAdd(&hl[b1i], 1);
        atomicAdd(&hl[b2i], 1);
        atomicAdd(&hl[b3i], 1);
    }
    __syncthreads();
    if (hl[t]) atomicAdd(&hist[t], hl[t]);
}

// ---------------- encoder via MFMA ----------------
// grid 8, 4 waves; wave handles rows blk*64 + w*16 + n. Three chained GEMMs
// with in-register LN and shfl-based C->B layout transforms (energy_v3 machinery).
__global__ __launch_bounds__(256) void encoder_mfma(
    const float* __restrict__ fo, const float* __restrict__ fr,
    const ushort* __restrict__ W1p, const ushort* __restrict__ W2p,
    const ushort* __restrict__ W3ap, const ushort* __restrict__ W3bp,
    const float* __restrict__ b1, const float* __restrict__ g1,
    const float* __restrict__ be1, const float* __restrict__ b2,
    ushort* __restrict__ ebf, ushort* __restrict__ A1bf, ushort* __restrict__ A2bf)
{
    int blk = blockIdx.x;
    int t = threadIdx.x;
    int w = t >> 6, lane = t & 63, q = lane >> 4, n = lane & 15;
    int r = blk * 64 + w * 16 + n;
    bool isOrig = (r < 256);
    const float* f = isOrig ? (fo + (size_t)r * 512) : (fr + (size_t)(r - 256) * 512);

    // ----- layer 1: X @ W1 -----
    f32x4 acc[16];
#pragma unroll
    for (int tt = 0; tt < 16; ++tt) acc[tt] = (f32x4){0.f, 0.f, 0.f, 0.f};
    for (int kk = 0; kk < 16; ++kk) {
        int kb = kk * 32 + q * 8;
        float4 fa = *(const float4*)(f + kb);
        float4 fb = *(const float4*)(f + kb + 4);
        U8 bb;
        bb.u[0] = (unsigned)f2bf(fa.x) | ((unsigned)f2bf(fa.y) << 16);
        bb.u[1] = (unsigned)f2bf(fa.z) | ((unsigned)f2bf(fa.w) << 16);
        bb.u[2] = (unsigned)f2bf(fb.x) | ((unsigned)f2bf(fb.y) << 16);
        bb.u[3] = (unsigned)f2bf(fb.z) | ((unsigned)f2bf(fb.w) << 16);
        const ushort* wp = W1p + ((size_t)(kk * 1024 + lane)) * 8;
#pragma unroll
        for (int tt = 0; tt < 16; ++tt) {
            short8 af = *(const short8*)(wp + (size_t)tt * 512);
            acc[tt] = __builtin_amdgcn_mfma_f32_16x16x32_bf16(af, bb.s, acc[tt], 0, 0, 0);
        }
    }
    // + b1, LN over 256 cols, relu, *g1+be1 -> pk
    float s1 = 0.f, s2 = 0.f;
#pragma unroll
    for (int tt = 0; tt < 16; ++tt) {
        int tb = tt * 16 + q * 4;
        float4 bv = *(const float4*)(b1 + tb);
        float v0 = acc[tt][0] + bv.x, v1 = acc[tt][1] + bv.y;
        float v2 = acc[tt][2] + bv.z, v3 = acc[tt][3] + bv.w;
        acc[tt][0] = v0; acc[tt][1] = v1; acc[tt][2] = v2; acc[tt][3] = v3;
        s1 += v0 + v1 + v2 + v3;
        s2 += v0 * v0 + v1 * v1 + v2 * v2 + v3 * v3;
    }
    s1 += __shfl_xor(s1, 16); s1 += __shfl_xor(s1, 32);
    s2 += __shfl_xor(s2, 16); s2 += __shfl_xor(s2, 32);
    float mean = s1 * (1.f / 256.f);
    float var = s2 * (1.f / 256.f) - mean * mean;
    float rstd = rsqrtf(var + 1e-5f);
    uint2 pk[16];
#pragma unroll
    for (int tt = 0; tt < 16; ++tt) {
        int tb = tt * 16 + q * 4;
        float4 gg = *(const float4*)(g1 + tb);
        float4 be = *(const float4*)(be1 + tb);
        float h0 = fmaxf((acc[tt][0] - mean) * rstd * gg.x + be.x, 0.f);
        float h1 = fmaxf((acc[tt][1] - mean) * rstd * gg.y + be.y, 0.f);
        float h2 = fmaxf((acc[tt][2] - mean) * rstd * gg.z + be.z, 0.f);
        float h3 = fmaxf((acc[tt][3] - mean) * rstd * gg.w + be.w, 0.f);
        pk[tt].x = (unsigned)f2bf(h0) | ((unsigned)f2bf(h1) << 16);
        pk[tt].y = (unsigned)f2bf(h2) | ((unsigned)f2bf(h3) << 16);
    }

    int qh = (q >> 1) & 1;
    int src0 = ((q & 1) * 2) * 16 + n;
    int src1 = src0 + 16;

    // ----- layer 2: H @ W2 -----
    f32x4 eacc[16];
#pragma unroll
    for (int tt = 0; tt < 16; ++tt) eacc[tt] = (f32x4){0.f, 0.f, 0.f, 0.f};
#pragma unroll
    for (int kk = 0; kk < 8; ++kk) {
        uint2 lo2 = pk[kk * 2], hi2 = pk[kk * 2 + 1];
        unsigned a0 = (unsigned)__shfl((int)lo2.x, src0);
        unsigned a1 = (unsigned)__shfl((int)lo2.y, src0);
        unsigned b0 = (unsigned)__shfl((int)hi2.x, src0);
        unsigned b1v = (unsigned)__shfl((int)hi2.y, src0);
        unsigned c0 = (unsigned)__shfl((int)lo2.x, src1);
        unsigned c1 = (unsigned)__shfl((int)lo2.y, src1);
        unsigned d0 = (unsigned)__shfl((int)hi2.x, src1);
        unsigned d1 = (unsigned)__shfl((int)hi2.y, src1);
        U8 hb;
        hb.u[0] = qh ? b0 : a0;
        hb.u[1] = qh ? b1v : a1;
        hb.u[2] = qh ? d0 : c0;
        hb.u[3] = qh ? d1 : c1;
        const ushort* wp = W2p + ((size_t)(kk * 1024 + lane)) * 8;
#pragma unroll
        for (int tt = 0; tt < 16; ++tt) {
            short8 af = *(const short8*)(wp + (size_t)tt * 512);
            eacc[tt] = __builtin_amdgcn_mfma_f32_16x16x32_bf16(af, hb.s, eacc[tt], 0, 0, 0);
        }
    }
    // + b2 -> e; store ebf; repack
    uint2 epk[16];
#pragma unroll
    for (int tt = 0; tt < 16; ++tt) {
        int tb = tt * 16 + q * 4;
        float4 bv = *(const float4*)(b2 + tb);
        float e0 = eacc[tt][0] + bv.x, e1 = eacc[tt][1] + bv.y;
        float e2 = eacc[tt][2] + bv.z, e3 = eacc[tt][3] + bv.w;
        epk[tt].x = (unsigned)f2bf(e0) | ((unsigned)f2bf(e1) << 16);
        epk[tt].y = (unsigned)f2bf(e2) | ((unsigned)f2bf(e3) << 16);
        *(uint2*)(ebf + (size_t)r * 256 + tb) = epk[tt];
    }

    // ----- layer 3: e @ W3a|W3b -----
    const ushort* W3x = isOrig ? W3ap : W3bp;
    f32x4 aacc[16];
#pragma unroll
    for (int tt = 0; tt < 16; ++tt) aacc[tt] = (f32x4){0.f, 0.f, 0.f, 0.f};
#pragma unroll
    for (int kk = 0; kk < 8; ++kk) {
        uint2 lo2 = epk[kk * 2], hi2 = epk[kk * 2 + 1];
        unsigned a0 = (unsigned)__shfl((int)lo2.x, src0);
        unsigned a1 = (unsigned)__shfl((int)lo2.y, src0);
        unsigned b0 = (unsigned)__shfl((int)hi2.x, src0);
        unsigned b1v = (unsigned)__shfl((int)hi2.y, src0);
        unsigned c0 = (unsigned)__shfl((int)lo2.x, src1);
        unsigned c1 = (unsigned)__shfl((int)lo2.y, src1);
        unsigned d0 = (unsigned)__shfl((int)hi2.x, src1);
        unsigned d1 = (unsigned)__shfl((int)hi2.y, src1);
        U8 hb;
        hb.u[0] = qh ? b0 : a0;
        hb.u[1] = qh ? b1v : a1;
        hb.u[2] = qh ? d0 : c0;
        hb.u[3] = qh ? d1 : c1;
        const ushort* wp = W3x + ((size_t)(kk * 1024 + lane)) * 8;
#pragma unroll
        for (int tt = 0; tt < 16; ++tt) {
            short8 af = *(const short8*)(wp + (size_t)tt * 512);
            aacc[tt] = __builtin_amdgcn_mfma_f32_16x16x32_bf16(af, hb.s, aacc[tt], 0, 0, 0);
        }
    }
    ushort* dst = isOrig ? (A1bf + (size_t)r * 256) : (A2bf + (size_t)(r - 256) * 256);
#pragma unroll
    for (int tt = 0; tt < 16; ++tt) {
        int tb = tt * 16 + q * 4;
        uint2 pv;
        pv.x = (unsigned)f2bf(aacc[tt][0]) | ((unsigned)f2bf(aacc[tt][1]) << 16);
        pv.y = (unsigned)f2bf(aacc[tt][2]) | ((unsigned)f2bf(aacc[tt][3]) << 16);
        *(uint2*)(dst + tb) = pv;
    }
}

// ---------------- fused sim + top5 ----------------
__global__ __launch_bounds__(256) void simtop_kernel(const float* __restrict__ fo,
                                                     const float* __restrict__ fr,
                                                     const float* __restrict__ rnorm,
                                                     const float* __restrict__ fT,
                                                     int* __restrict__ top5) {
    int b = blockIdx.x;
    int pass = b >> 7, pair = b & 127;
    int i0 = pair * 2, i1 = i0 + 1;
    const float* f = pass ? fr : fo;
    const float* rn = rnorm + pass * 256;
    __shared__ float2 fs2[512];
    __shared__ float candV[4][2][5];
    __shared__ int candI[4][2][5];
    int t = threadIdx.x;
    const float* f0 = f + (size_t)i0 * 512;
    const float* f1 = f + (size_t)i1 * 512;
    fs2[t] = make_float2(f0[t], f1[t]);
    fs2[t + 256] = make_float2(f0[t + 256], f1[t + 256]);
    __syncthreads();
    int j = t;
    const float* col = fT + (size_t)pass * 131072 + j;
    float x0 = 0.f, x1 = 0.f, y0 = 0.f, y1 = 0.f, z0 = 0.f, z1 = 0.f, u0 = 0.f, u1 = 0.f;
#pragma unroll 8
    for (int k = 0; k < 128; ++k) {
        float v0 = col[(size_t)k * 256];
        float v1 = col[(size_t)(k + 128) * 256];
        float v2 = col[(size_t)(k + 256) * 256];
        float v3 = col[(size_t)(k + 384) * 256];
        float2 g0 = fs2[k], g1 = fs2[k + 128], g2 = fs2[k + 256], g3 = fs2[k + 384];
        x0 += g0.x * v0; x1 += g0.y * v0;
        y0 += g1.x * v1; y1 += g1.y * v1;
        z0 += g2.x * v2; z1 += g2.y * v2;
        u0 += g3.x * v3; u1 += g3.y * v3;
    }
    float a0 = (x0 + y0) + (z0 + u0);
    float a1 = (x1 + y1) + (z1 + u1);
    float rnj = rn[j];
    a0 *= rnj;
    a1 *= rnj;
    if (j == i0) a0 = -INFINITY;
    if (j == i1) a1 = -INFINITY;
    int w = t >> 6, lane = t & 63;
    for (int sel = 0; sel < 2; ++sel) {
        float v2 = sel ? a1 : a0;
        int idx = j;
        for (int r = 0; r < 5; ++r) {
            float m = v2;
            int mi = idx;
#pragma unroll
            for (int off = 32; off > 0; off >>= 1) {
                float om = __shfl_xor(m, off);
                int omi = __shfl_xor(mi, off);
                if (om > m || (om == m && omi < mi)) { m = om; mi = omi; }
            }
            if (lane == 0) { candV[w][sel][r] = m; candI[w][sel][r] = mi; }
            if (idx == mi) v2 = -INFINITY;
        }
    }
    __syncthreads();
    if (w < 2) {
        float v = -INFINITY;
        int ix = 0x7fffffff;
        if (lane < 20) { v = candV[lane / 5][w][lane % 5]; ix = candI[lane / 5][w][lane % 5]; }
        int iSel = w ? i1 : i0;
        for (int r = 0; r < 5; ++r) {
            float m = v;
            int mi = ix;
#pragma unroll
            for (int off = 32; off > 0; off >>= 1) {
                float om = __shfl_xor(m, off);
                int omi = __shfl_xor(mi, off);
                if (om > m || (om == m && omi < mi)) { m = om; mi = omi; }
            }
            if (lane == 0) top5[((size_t)pass * 256 + iSel) * 5 + r] = mi;
            if (ix == mi) v = -INFINITY;
        }
    }
}

// ---------------- energy: barrier-free, LDS-free MFMA ----------------
__global__ __launch_bounds__(256, 1) void energy_v3(
    const ushort* __restrict__ A1bf, const ushort* __restrict__ A2bf,
    const ushort* __restrict__ ebf,
    const ushort* __restrict__ W3p, const ushort* __restrict__ W4p,
    const float* __restrict__ b3, const float* __restrict__ g3, const float* __restrict__ be3,
    const float* __restrict__ b4, const float* __restrict__ W5, const float* __restrict__ b5,
    ushort* __restrict__ E)
{
    int i = blockIdx.x;
    int t = threadIdx.x;
    int w = t >> 6, lane = t & 63, q = lane >> 4, n = lane & 15;
    int jb = w * 64;
    __shared__ float combS[256], g3S[256], be3S[256], b4S[128], w5S[128];
    combS[t] = bf2f(A1bf[(size_t)i * 256 + t]) + b3[t];
    g3S[t] = g3[t];
    be3S[t] = be3[t];
    if (t < 128) { b4S[t] = b4[t]; w5S[t] = W5[t]; }
    __syncthreads();

    const ushort* e1p = ebf + (size_t)i * 256;
    const ushort* e2p = ebf + 65536;

    f32x4 acc[4][16];
#pragma unroll
    for (int s = 0; s < 4; ++s)
#pragma unroll
        for (int tt = 0; tt < 16; ++tt) acc[s][tt] = (f32x4){0.f, 0.f, 0.f, 0.f};

    for (int kk = 0; kk < 8; ++kk) {
        int kbase = kk * 32 + q * 8;
        U8 e1v;
        e1v.v = *(const u32x4*)(e1p + kbase);
        float e1f[8];
#pragma unroll
        for (int x = 0; x < 4; ++x) {
            e1f[2 * x] = bflo(e1v.u[x]);
            e1f[2 * x + 1] = bfhi(e1v.u[x]);
        }
        short8 bfrag[4];
#pragma unroll
        for (int s = 0; s < 4; ++s) {
            U8 e2v;
            e2v.v = *(const u32x4*)(e2p + (size_t)(jb + s * 16 + n) * 256 + kbase);
            U8 bb;
#pragma unroll
            for (int x = 0; x < 4; ++x) {
                float p0 = bflo(e2v.u[x]) * e1f[2 * x];
                float p1 = bfhi(e2v.u[x]) * e1f[2 * x + 1];
                bb.u[x] = (unsigned)f2bf(p0) | ((unsigned)f2bf(p1) << 16);
            }
            bfrag[s] = bb.s;
        }
        const ushort* wp = W3p + ((size_t)(kk * 16) * 64 + lane) * 8;
#pragma unroll
        for (int tt = 0; tt < 16; ++tt) {
            short8 af = *(const short8*)(wp + (size_t)tt * 512);
#pragma unroll
            for (int s = 0; s < 4; ++s)
                acc[s][tt] = __builtin_amdgcn_mfma_f32_16x16x32_bf16(af, bfrag[s], acc[s][tt], 0, 0, 0);
        }
    }

    uint2 pk[4][16];
    float b5v = b5[0];
#pragma unroll
    for (int s = 0; s < 4; ++s) {
        int j = jb + s * 16 + n;
        float s1 = 0.f, s2 = 0.f;
#pragma unroll
        for (int tt = 0; tt < 16; ++tt) {
            int tb = tt * 16 + q * 4;
            float4 cb = *(const float4*)(combS + tb);
            uint2 a2u = *(const uint2*)(A2bf + (size_t)j * 256 + tb);
            float a0 = bflo(a2u.x), a1f = bfhi(a2u.x), a2f = bflo(a2u.y), a3f = bfhi(a2u.y);
            float v0 = acc[s][tt][0] + cb.x + a0;
            float v1 = acc[s][tt][1] + cb.y + a1f;
            float v2 = acc[s][tt][2] + cb.z + a2f;
            float v3 = acc[s][tt][3] + cb.w + a3f;
            acc[s][tt][0] = v0; acc[s][tt][1] = v1; acc[s][tt][2] = v2; acc[s][tt][3] = v3;
            s1 += v0 + v1 + v2 + v3;
            s2 += v0 * v0 + v1 * v1 + v2 * v2 + v3 * v3;
        }
        s1 += __shfl_xor(s1, 16); s1 += __shfl_xor(s1, 32);
        s2 += __shfl_xor(s2, 16); s2 += __shfl_xor(s2, 32);
        float mean = s1 * (1.f / 256.f);
        float var = s2 * (1.f / 256.f) - mean * mean;
        float rstd = rsqrtf(var + 1e-5f);
#pragma unroll
        for (int tt = 0; tt < 16; ++tt) {
            int tb = tt * 16 + q * 4;
            float4 gg = *(const float4*)(g3S + tb);
            float4 be = *(const float4*)(be3S + tb);
            float h0 = fmaxf((acc[s][tt][0] - mean) * rstd * gg.x + be.x, 0.f);
            float h1 = fmaxf((acc[s][tt][1] - mean) * rstd * gg.y + be.y, 0.f);
            float h2 = fmaxf((acc[s][tt][2] - mean) * rstd * gg.z + be.z, 0.f);
            float h3 = fmaxf((acc[s][tt][3] - mean) * rstd * gg.w + be.w, 0.f);
            pk[s][tt].x = (unsigned)f2bf(h0) | ((unsigned)f2bf(h1) << 16);
            pk[s][tt].y = (unsigned)f2bf(h2) | ((unsigned)f2bf(h3) << 16);
        }
    }

    f32x4 gacc[4][8];
#pragma unroll
    for (int s = 0; s < 4; ++s)
#pragma unroll
        for (int nt = 0; nt < 8; ++nt) gacc[s][nt] = (f32x4){0.f, 0.f, 0.f, 0.f};

    int qh = (q >> 1) & 1;
    int src0 = ((q & 1) * 2) * 16 + n;
    int src1 = src0 + 16;
#pragma unroll
    for (int kk = 0; kk < 8; ++kk) {
        short8 wa[8];
        const ushort* wp = W4p + ((size_t)(kk * 8) * 64 + lane) * 8;
#pragma unroll
        for (int nt = 0; nt < 8; ++nt) wa[nt] = *(const short8*)(wp + (size_t)nt * 512);
#pragma unroll
        for (int s = 0; s < 4; ++s) {
            uint2 lo2 = pk[s][kk * 2], hi2 = pk[s][kk * 2 + 1];
            unsigned a0 = (unsigned)__shfl((int)lo2.x, src0);
            unsigned a1 = (unsigned)__shfl((int)lo2.y, src0);
            unsigned b0 = (unsigned)__shfl((int)hi2.x, src0);
            unsigned b1 = (unsigned)__shfl((int)hi2.y, src0);
            unsigned c0 = (unsigned)__shfl((int)lo2.x, src1);
            unsigned c1 = (unsigned)__shfl((int)lo2.y, src1);
            unsigned d0 = (unsigned)__shfl((int)hi2.x, src1);
            unsigned d1 = (unsigned)__shfl((int)hi2.y, src1);
            U8 hb;
            hb.u[0] = qh ? b0 : a0;
            hb.u[1] = qh ? b1 : a1;
            hb.u[2] = qh ? d0 : c0;
            hb.u[3] = qh ? d1 : c1;
#pragma unroll
            for (int nt = 0; nt < 8; ++nt)
                gacc[s][nt] = __builtin_amdgcn_mfma_f32_16x16x32_bf16(wa[nt], hb.s, gacc[s][nt], 0, 0, 0);
        }
    }

#pragma unroll
    for (int s = 0; s < 4; ++s) {
        float ep = 0.f;
#pragma unroll
        for (int nt = 0; nt < 8; ++nt) {
            int nb = nt * 16 + q * 4;
            float4 b4v = *(const float4*)(b4S + nb);
            float4 w5v = *(const float4*)(w5S + nb);
            ep += fmaxf(gacc[s][nt][0] + b4v.x, 0.f) * w5v.x;
            ep += fmaxf(gacc[s][nt][1] + b4v.y, 0.f) * w5v.y;
            ep += fmaxf(gacc[s][nt][2] + b4v.z, 0.f) * w5v.z;
            ep += fmaxf(gacc[s][nt][3] + b4v.w, 0.f) * w5v.w;
        }
        ep += __shfl_xor(ep, 16);
        ep += __shfl_xor(ep, 32);
        if (q == 0) E[(size_t)i * 256 + jb + s * 16 + n] = f2bf(ep + b5v);
    }
}

// ---------------- margin + jaccard ----------------
__global__ void margin_jac_kernel(const ushort* __restrict__ E, const int* __restrict__ top5,
                                  float* slAcc, float* jacOut) {
    __shared__ float red[4];
    int b = blockIdx.x, t = threadIdx.x;
    if (b < 256) {
        float diag = bf2f(E[(size_t)b * 256 + b]);
        float l = (t == b) ? 0.f : fmaxf(1.f + bf2f(E[(size_t)b * 256 + t]) - diag, 0.f);
        float tot = block_sum256(l, red);
        if (t == 0) atomicAdd(slAcc, tot);
    } else {
        int O[5], R[5];
#pragma unroll
        for (int r = 0; r < 5; ++r) {
            O[r] = top5[t * 5 + r];
            R[r] = top5[(256 + t) * 5 + r];
        }
        int inter = 0;
#pragma unroll
        for (int a = 0; a < 5; ++a)
#pragma unroll
            for (int bq = 0; bq < 5; ++bq) inter += (O[a] == R[bq]);
        float fi2 = (float)inter;
        float jac = fi2 / (10.f - fi2 + 1e-8f);
        float s = block_sum256(jac, red);
        if (t == 0) jacOut[0] = s;
    }
}

// ---------------- finalize ----------------
__global__ void finalize_kernel(const float* wsf, const int* h1, const int* h2, float* out) {
    __shared__ float red[4];
    int t = threadIdx.x;
    float p1 = (float)h1[t] / 4194304.f;
    float p2 = (float)h2[t] / 2097152.f;
    float s1 = block_sum256(-p1 * log2f(p1 + 1e-8f), red);
    float s2 = block_sum256(-p2 * log2f(p2 + 1e-8f), red);
    if (t == 0) {
        float recon = wsf[0] / 3145728.f;
        float sp = 0.5f * (wsf[1] / 4194304.f + wsf[2] / 2097152.f);
        float en = 0.5f * (s1 + s2);
        float compress = sp + 0.1f * en;
        float sl = wsf[5] / (256.f * 255.f);
        float nl = 1.f - wsf[6] / 256.f;
        float energy = sl + 0.3f * nl;
        float total = recon + 0.01f * compress + 0.1f * energy;
        out[0] = total;
        out[1] = recon;
        out[2] = energy;
        out[3] = compress;
    }
}

// ---------------- launch ----------------
extern "C" void kernel_launch(void* const* d_in, const int* in_sizes, int n_in,
                              void* d_out, int out_size, void* d_ws, size_t ws_size,
                              hipStream_t stream) {
    const float* outputs = (const float*)d_in[0];
    const float* images  = (const float*)d_in[1];
    const float* f_orig  = (const float*)d_in[2];
    const float* f_recon = (const float*)d_in[3];
    const float* cf1 = (const float*)d_in[4];
    const float* cf2 = (const float*)d_in[5];
    const float* W1 = (const float*)d_in[6];
    const float* b1 = (const float*)d_in[7];
    const float* g1 = (const float*)d_in[8];
    const float* be1 = (const float*)d_in[9];
    const float* W2 = (const float*)d_in[10];
    const float* b2 = (const float*)d_in[11];
    const float* W3 = (const float*)d_in[12];
    const float* b3 = (const float*)d_in[13];
    const float* g3 = (const float*)d_in[14];
    const float* be3 = (const float*)d_in[15];
    const float* W4 = (const float*)d_in[16];
    const float* b4 = (const float*)d_in[17];
    const float* W5 = (const float*)d_in[18];
    const float* b5 = (const float*)d_in[19];

    float* wsf = (float*)d_ws;
    unsigned* wsu = (unsigned*)d_ws;
    int* wsi = (int*)d_ws;
    float* out = (float*)d_out;

    float* rnorm = wsf + 528;
    ushort* A1bf = (ushort*)(wsf + 1040);
    ushort* A2bf = (ushort*)(wsf + 33808);
    ushort* ebf  = (ushort*)(wsf + 66576);
    ushort* Ebf  = (ushort*)(wsf + 132112);
    ushort* W3cpk = (ushort*)(wsf + 164880);
    ushort* W4pk  = (ushort*)(wsf + 197648);
    ushort* W1pk  = (ushort*)(wsf + 214032);
    ushort* W2pk  = (ushort*)(wsf + 279568);
    ushort* W3apk = (ushort*)(wsf + 312336);
    ushort* W3bpk = (ushort*)(wsf + 345104);
    float* fT = wsf + 377872;
    int* top5 = wsi + 640016;

    hipLaunchKernelGGL(init_kernel, dim3(1), dim3(256), 0, stream, wsf, wsu, wsi);
    hipLaunchKernelGGL(mega_kernel, dim3(2384), dim3(256), 0, stream,
                       (const float4*)outputs, (const float4*)images,
                       (const float4*)cf1, (const float4*)cf2,
                       f_orig, f_recon, W1, W2, W3, W4,
                       wsf, wsu, rnorm, fT, W3cpk, W4pk, W1pk, W2pk, W3apk, W3bpk);
    hipLaunchKernelGGL(hist_kernel, dim3(1024), dim3(256), 0, stream,
                       (const float4*)cf1, (const float4*)cf2, wsu, wsi);
    hipLaunchKernelGGL(encoder_mfma, dim3(8), dim3(256), 0, stream,
                       f_orig, f_recon, W1pk, W2pk, W3apk, W3bpk,
                       b1, g1, be1, b2, ebf, A1bf, A2bf);
    hipLaunchKernelGGL(simtop_kernel, dim3(256), dim3(256), 0, stream,
                       f_orig, f_recon, rnorm, fT, top5);
    hipLaunchKernelGGL(energy_v3, dim3(256), dim3(256), 0, stream,
                       A1bf, A2bf, ebf, W3cpk, W4pk, b3, g3, be3, b4, W5, b5, Ebf);
    hipLaunchKernelGGL(margin_jac_kernel, dim3(257), dim3(256), 0, stream,
                       Ebf, top5, wsf + 5, wsf + 6);
    hipLaunchKernelGGL(finalize_kernel, dim3(1), dim3(256), 0, stream,
                       wsf, wsi + 16, wsi + 272, out);
}

// Round 6
// 343.061 us; speedup vs baseline: 1.2058x; 1.2058x over previous
//
#include <hip/hip_runtime.h>
#include <math.h>

typedef __attribute__((ext_vector_type(8))) short short8;
typedef __attribute__((ext_vector_type(4))) float f32x4;
typedef __attribute__((ext_vector_type(4))) unsigned int u32x4;

union U8 { unsigned int u[4]; short8 s; u32x4 v; };

// ---------------- helpers ----------------

__device__ __forceinline__ float wave_sum(float v) {
#pragma unroll
    for (int o = 32; o > 0; o >>= 1) v += __shfl_down(v, o);
    return v;
}

__device__ __forceinline__ float block_sum256(float v, float* red) {
    v = wave_sum(v);
    int t = threadIdx.x;
    if ((t & 63) == 0) red[t >> 6] = v;
    __syncthreads();
    float r = red[0] + red[1] + red[2] + red[3];
    __syncthreads();
    return r;
}

__device__ __forceinline__ unsigned fenc(float f) {
    unsigned u = __float_as_uint(f);
    return (u & 0x80000000u) ? ~u : (u | 0x80000000u);
}
__device__ __forceinline__ float fdec(unsigned u) {
    return (u & 0x80000000u) ? __uint_as_float(u & 0x7fffffffu) : __uint_as_float(~u);
}

__device__ __forceinline__ ushort f2bf(float f) {
    unsigned u = __float_as_uint(f);
    unsigned r = (u + 0x7fffu + ((u >> 16) & 1u)) >> 16;
    return (ushort)r;
}
__device__ __forceinline__ float bflo(unsigned u) { return __uint_as_float(u << 16); }
__device__ __forceinline__ float bfhi(unsigned u) { return __uint_as_float(u & 0xffff0000u); }
__device__ __forceinline__ float bf2f(ushort u) { return __uint_as_float((unsigned)u << 16); }

// ---------------- ws float layout ----------------
// 0..527 scalars + hists (ints)
// 528 rnorm[512] -> 1040
// 1040 A1bf (65536 bf16) -> 33808
// 33808 A2bf (65536 bf16) -> 66576
// 66576 ebf (131072 bf16) -> 132112
// 132112 Ebf (65536 bf16) -> 164880
// 164880 W3cpk -> 197648, 197648 W4pk -> 214032
// 214032 W1pk -> 279568, 279568 W2pk -> 312336
// 312336 W3apk -> 345104, 345104 W3bpk -> 377872
// 377872 fT fp32[262144] -> 640016
// 640016 top5 int[2560] -> 642576

__global__ void init_kernel(float* wsf, unsigned* wsu, int* wsi) {
    int t = threadIdx.x;
    if (t < 7) wsf[t] = 0.f;
    if (t == 7 || t == 9) wsu[t] = 0xFFFFFFFFu;
    if (t == 8 || t == 10) wsu[t] = 0u;
    wsi[16 + t] = 0;
    wsi[272 + t] = 0;
}

// pack a [K x 256] fp32 matrix into bf16 A-fragment order
__device__ __forceinline__ void pack256(const float* __restrict__ src, ushort* __restrict__ dst, int s) {
    int lane = s & 63;
    int tt = (s >> 6) & 15;
    int kk = s >> 10;
    int qq = lane >> 4, nn = lane & 15;
    int tcol = tt * 16 + nn;
    short8 v;
#pragma unroll
    for (int jj = 0; jj < 8; ++jj) {
        int k = kk * 32 + qq * 8 + jj;
        v[jj] = (short)f2bf(src[(size_t)k * 256 + tcol]);
    }
    *(short8*)(dst + (size_t)s * 8) = v;
}

__device__ __forceinline__ void pack128(const float* __restrict__ src, ushort* __restrict__ dst, int s) {
    int lane = s & 63;
    int tt = (s >> 6) & 7;
    int kk = s >> 9;
    int qq = lane >> 4, nn = lane & 15;
    int ncol = tt * 16 + nn;
    short8 v;
#pragma unroll
    for (int jj = 0; jj < 8; ++jj) {
        int k = kk * 32 + qq * 8 + jj;
        v[jj] = (short)f2bf(src[(size_t)k * 128 + ncol]);
    }
    *(short8*)(dst + (size_t)s * 8) = v;
}

// ---------------- mega: stats + transpose + packs ----------------
__global__ __launch_bounds__(256) void mega_kernel(
    const float4* __restrict__ o, const float4* __restrict__ im,
    const float4* __restrict__ cf1, const float4* __restrict__ cf2,
    const float* __restrict__ fo, const float* __restrict__ fr,
    const float* __restrict__ W1, const float* __restrict__ W2,
    const float* __restrict__ W3, const float* __restrict__ W4,
    float* wsf, unsigned* wsu, float* rnorm, float* fT,
    ushort* __restrict__ W3cpk, ushort* __restrict__ W4pk,
    ushort* __restrict__ W1pk, ushort* __restrict__ W2pk,
    ushort* __restrict__ W3apk, ushort* __restrict__ W3bpk) {
    __shared__ float smem[64 * 33];
    float* red = smem;
    int b = blockIdx.x, t = threadIdx.x;
    if (b < 2048) {
        if (b < 512) {
            // recon: contiguous 1536 float4 per block, 6 unrolled iters
            int base = b * 1536 + t;
            float4 av[6], cv[6];
#pragma unroll
            for (int u = 0; u < 6; ++u) { av[u] = o[base + u * 256]; cv[u] = im[base + u * 256]; }
            float s0 = 0.f, s1 = 0.f;
#pragma unroll
            for (int u = 0; u < 6; ++u) {
                float dx = av[u].x - cv[u].x, dy = av[u].y - cv[u].y;
                float dz = av[u].z - cv[u].z, dw = av[u].w - cv[u].w;
                if (u & 1) s1 += dx * dx + dy * dy + dz * dz + dw * dw;
                else s0 += dx * dx + dy * dy + dz * dz + dw * dw;
            }
            float tot = block_sum256(s0 + s1, red);
            if (t == 0) atomicAdd(wsf + 0, tot);
        } else if (b < 1536) {
            int which = (b < 1024) ? 0 : 1;
            const float4* x = which ? cf2 : cf1;
            int niter = which ? 4 : 8;
            int base = which ? ((b - 1024) * 1024 + t) : ((b - 512) * 2048 + t);
            float4 v[8];
            for (int u = 0; u < niter; ++u) v[u] = x[base + u * 256];
            float s = 0.f, mn = INFINITY, mx = -INFINITY;
            for (int u = 0; u < niter; ++u) {
                float4 a = v[u];
                s += fabsf(a.x) + fabsf(a.y) + fabsf(a.z) + fabsf(a.w);
                mn = fminf(mn, fminf(fminf(a.x, a.y), fminf(a.z, a.w)));
                mx = fmaxf(mx, fmaxf(fmaxf(a.x, a.y), fmaxf(a.z, a.w)));
            }
            float tot = block_sum256(s, red);
#pragma unroll
            for (int off = 32; off > 0; off >>= 1) {
                mn = fminf(mn, __shfl_down(mn, off));
                mx = fmaxf(mx, __shfl_down(mx, off));
            }
            float* rmn = smem + 8;
            float* rmx = smem + 16;
            if ((t & 63) == 0) { rmn[t >> 6] = mn; rmx[t >> 6] = mx; }
            __syncthreads();
            if (t == 0) {
                atomicAdd(wsf + 1 + which, tot);
                float m1 = fminf(fminf(rmn[0], rmn[1]), fminf(rmn[2], rmn[3]));
                float m2 = fmaxf(fmaxf(rmx[0], rmx[1]), fmaxf(rmx[2], rmx[3]));
                atomicMin(wsu + 7 + which * 2, fenc(m1));
                atomicMax(wsu + 8 + which * 2, fenc(m2));
            }
        } else {
            int r = b - 1536;
            const float4* f = (r < 256) ? ((const float4*)fo + (size_t)r * 128)
                                        : ((const float4*)fr + (size_t)(r - 256) * 128);
            float s = 0.f;
            if (t < 128) {
                float4 a = f[t];
                s = a.x * a.x + a.y * a.y + a.z * a.z + a.w * a.w;
            }
            float tot = block_sum256(s, red);
            if (t == 0) rnorm[r] = 1.0f / sqrtf(tot);
        }
    } else if (b < 2176) {
        // transpose: fT[pass][k][j] = f[j][k]
        int bb = b - 2048;
        int pass = bb >> 6;
        int kt = (bb >> 2) & 15;
        int jt = bb & 3;
        int k0 = kt * 32, j0 = jt * 64;
        const float* f = pass ? fr : fo;
        float (*tile)[33] = (float(*)[33])smem;
        int cl = t & 31, rl = t >> 5;
#pragma unroll
        for (int r = 0; r < 8; ++r) {
            int row = j0 + rl + r * 8;
            tile[rl + r * 8][cl] = f[(size_t)row * 512 + k0 + cl];
        }
        __syncthreads();
        int jl = t & 63, kq = t >> 6;
        float* dst = fT + (size_t)pass * 131072;
#pragma unroll
        for (int c = 0; c < 8; ++c) {
            int kl = kq * 8 + c;
            dst[(size_t)(k0 + kl) * 256 + j0 + jl] = tile[jl][kl];
        }
    } else {
        int pb = b - 2176;
        if (pb < 32) pack256(W3 + 512 * 256, W3cpk, pb * 256 + t);
        else if (pb < 48) pack128(W4, W4pk, (pb - 32) * 256 + t);
        else if (pb < 112) pack256(W1, W1pk, (pb - 48) * 256 + t);
        else if (pb < 144) pack256(W2, W2pk, (pb - 112) * 256 + t);
        else if (pb < 176) pack256(W3, W3apk, (pb - 144) * 256 + t);
        else pack256(W3 + 256 * 256, W3bpk, (pb - 176) * 256 + t);
    }
}

// ---------------- merged histogram ----------------
__global__ __launch_bounds__(256) void hist_kernel(const float4* __restrict__ cf1,
                                                   const float4* __restrict__ cf2,
                                                   const unsigned* wsu, int* wsi) {
    __shared__ int hl[256];
    int b = blockIdx.x, t = threadIdx.x;
    hl[t] = 0;
    __syncthreads();
    int which = (b < 512) ? 0 : 1;
    const float4* x = which ? cf2 : cf1;
    int niter = which ? 4 : 8;
    int base = which ? ((b - 512) * 1024 + t) : (b * 2048 + t);
    int* hist = wsi + (which ? 272 : 16);
    float mn = fdec(wsu[7 + which * 2]), mx = fdec(wsu[8 + which * 2]);
    float inv = 256.f / (mx - mn + 1e-8f);
    float4 v[8];
    for (int u = 0; u < niter; ++u) v[u] = x[base + u * 256];
    for (int u = 0; u < niter; ++u) {
        float4 a = v[u];
        int b0i = min(max((int)floorf((a.x - mn) * inv), 0), 255);
        int b1i = min(max((int)floorf((a.y - mn) * inv), 0), 255);
        int b2i = min(max((int)floorf((a.z - mn) * inv), 0), 255);
        int b3i = min(max((int)floorf((a.w - mn) * inv), 0), 255);
        atomicAdd(&hl[b0i], 1);
        atomicAdd(&hl[b1i], 1);
        atomicAdd(&hl[b2i], 1);
        atomicAdd(&hl[b3i], 1);
    }
    __syncthreads();
    if (hl[t]) atomicAdd(&hist[t], hl[t]);
}

// ---------------- encoder via MFMA ----------------
__global__ __launch_bounds__(256) void encoder_mfma(
    const float* __restrict__ fo, const float* __restrict__ fr,
    const ushort* __restrict__ W1p, const ushort* __restrict__ W2p,
    const ushort* __restrict__ W3ap, const ushort* __restrict__ W3bp,
    const float* __restrict__ b1, const float* __restrict__ g1,
    const float* __restrict__ be1, const float* __restrict__ b2,
    ushort* __restrict__ ebf, ushort* __restrict__ A1bf, ushort* __restrict__ A2bf)
{
    int blk = blockIdx.x;
    int t = threadIdx.x;
    int w = t >> 6, lane = t & 63, q = lane >> 4, n = lane & 15;
    int r = blk * 64 + w * 16 + n;
    bool isOrig = (r < 256);
    const float* f = isOrig ? (fo + (size_t)r * 512) : (fr + (size_t)(r - 256) * 512);

    // layer 1: X @ W1
    f32x4 acc[16];
#pragma unroll
    for (int tt = 0; tt < 16; ++tt) acc[tt] = (f32x4){0.f, 0.f, 0.f, 0.f};
    for (int kk = 0; kk < 16; ++kk) {
        int kb = kk * 32 + q * 8;
        float4 fa = *(const float4*)(f + kb);
        float4 fb = *(const float4*)(f + kb + 4);
        U8 bb;
        bb.u[0] = (unsigned)f2bf(fa.x) | ((unsigned)f2bf(fa.y) << 16);
        bb.u[1] = (unsigned)f2bf(fa.z) | ((unsigned)f2bf(fa.w) << 16);
        bb.u[2] = (unsigned)f2bf(fb.x) | ((unsigned)f2bf(fb.y) << 16);
        bb.u[3] = (unsigned)f2bf(fb.z) | ((unsigned)f2bf(fb.w) << 16);
        const ushort* wp = W1p + ((size_t)(kk * 1024 + lane)) * 8;
#pragma unroll
        for (int tt = 0; tt < 16; ++tt) {
            short8 af = *(const short8*)(wp + (size_t)tt * 512);
            acc[tt] = __builtin_amdgcn_mfma_f32_16x16x32_bf16(af, bb.s, acc[tt], 0, 0, 0);
        }
    }
    float s1 = 0.f, s2 = 0.f;
#pragma unroll
    for (int tt = 0; tt < 16; ++tt) {
        int tb = tt * 16 + q * 4;
        float4 bv = *(const float4*)(b1 + tb);
        float v0 = acc[tt][0] + bv.x, v1 = acc[tt][1] + bv.y;
        float v2 = acc[tt][2] + bv.z, v3 = acc[tt][3] + bv.w;
        acc[tt][0] = v0; acc[tt][1] = v1; acc[tt][2] = v2; acc[tt][3] = v3;
        s1 += v0 + v1 + v2 + v3;
        s2 += v0 * v0 + v1 * v1 + v2 * v2 + v3 * v3;
    }
    s1 += __shfl_xor(s1, 16); s1 += __shfl_xor(s1, 32);
    s2 += __shfl_xor(s2, 16); s2 += __shfl_xor(s2, 32);
    float mean = s1 * (1.f / 256.f);
    float var = s2 * (1.f / 256.f) - mean * mean;
    float rstd = rsqrtf(var + 1e-5f);
    uint2 pk[16];
#pragma unroll
    for (int tt = 0; tt < 16; ++tt) {
        int tb = tt * 16 + q * 4;
        float4 gg = *(const float4*)(g1 + tb);
        float4 be = *(const float4*)(be1 + tb);
        float h0 = fmaxf((acc[tt][0] - mean) * rstd * gg.x + be.x, 0.f);
        float h1 = fmaxf((acc[tt][1] - mean) * rstd * gg.y + be.y, 0.f);
        float h2 = fmaxf((acc[tt][2] - mean) * rstd * gg.z + be.z, 0.f);
        float h3 = fmaxf((acc[tt][3] - mean) * rstd * gg.w + be.w, 0.f);
        pk[tt].x = (unsigned)f2bf(h0) | ((unsigned)f2bf(h1) << 16);
        pk[tt].y = (unsigned)f2bf(h2) | ((unsigned)f2bf(h3) << 16);
    }

    int qh = (q >> 1) & 1;
    int src0 = ((q & 1) * 2) * 16 + n;
    int src1 = src0 + 16;

    // layer 2: H @ W2
    f32x4 eacc[16];
#pragma unroll
    for (int tt = 0; tt < 16; ++tt) eacc[tt] = (f32x4){0.f, 0.f, 0.f, 0.f};
#pragma unroll
    for (int kk = 0; kk < 8; ++kk) {
        uint2 lo2 = pk[kk * 2], hi2 = pk[kk * 2 + 1];
        unsigned a0 = (unsigned)__shfl((int)lo2.x, src0);
        unsigned a1 = (unsigned)__shfl((int)lo2.y, src0);
        unsigned b0 = (unsigned)__shfl((int)hi2.x, src0);
        unsigned b1v = (unsigned)__shfl((int)hi2.y, src0);
        unsigned c0 = (unsigned)__shfl((int)lo2.x, src1);
        unsigned c1 = (unsigned)__shfl((int)lo2.y, src1);
        unsigned d0 = (unsigned)__shfl((int)hi2.x, src1);
        unsigned d1 = (unsigned)__shfl((int)hi2.y, src1);
        U8 hb;
        hb.u[0] = qh ? b0 : a0;
        hb.u[1] = qh ? b1v : a1;
        hb.u[2] = qh ? d0 : c0;
        hb.u[3] = qh ? d1 : c1;
        const ushort* wp = W2p + ((size_t)(kk * 1024 + lane)) * 8;
#pragma unroll
        for (int tt = 0; tt < 16; ++tt) {
            short8 af = *(const short8*)(wp + (size_t)tt * 512);
            eacc[tt] = __builtin_amdgcn_mfma_f32_16x16x32_bf16(af, hb.s, eacc[tt], 0, 0, 0);
        }
    }
    uint2 epk[16];
#pragma unroll
    for (int tt = 0; tt < 16; ++tt) {
        int tb = tt * 16 + q * 4;
        float4 bv = *(const float4*)(b2 + tb);
        float e0 = eacc[tt][0] + bv.x, e1 = eacc[tt][1] + bv.y;
        float e2 = eacc[tt][2] + bv.z, e3 = eacc[tt][3] + bv.w;
        epk[tt].x = (unsigned)f2bf(e0) | ((unsigned)f2bf(e1) << 16);
        epk[tt].y = (unsigned)f2bf(e2) | ((unsigned)f2bf(e3) << 16);
        *(uint2*)(ebf + (size_t)r * 256 + tb) = epk[tt];
    }

    // layer 3: e @ W3a|W3b
    const ushort* W3x = isOrig ? W3ap : W3bp;
    f32x4 aacc[16];
#pragma unroll
    for (int tt = 0; tt < 16; ++tt) aacc[tt] = (f32x4){0.f, 0.f, 0.f, 0.f};
#pragma unroll
    for (int kk = 0; kk < 8; ++kk) {
        uint2 lo2 = epk[kk * 2], hi2 = epk[kk * 2 + 1];
        unsigned a0 = (unsigned)__shfl((int)lo2.x, src0);
        unsigned a1 = (unsigned)__shfl((int)lo2.y, src0);
        unsigned b0 = (unsigned)__shfl((int)hi2.x, src0);
        unsigned b1v = (unsigned)__shfl((int)hi2.y, src0);
        unsigned c0 = (unsigned)__shfl((int)lo2.x, src1);
        unsigned c1 = (unsigned)__shfl((int)lo2.y, src1);
        unsigned d0 = (unsigned)__shfl((int)hi2.x, src1);
        unsigned d1 = (unsigned)__shfl((int)hi2.y, src1);
        U8 hb;
        hb.u[0] = qh ? b0 : a0;
        hb.u[1] = qh ? b1v : a1;
        hb.u[2] = qh ? d0 : c0;
        hb.u[3] = qh ? d1 : c1;
        const ushort* wp = W3x + ((size_t)(kk * 1024 + lane)) * 8;
#pragma unroll
        for (int tt = 0; tt < 16; ++tt) {
            short8 af = *(const short8*)(wp + (size_t)tt * 512);
            aacc[tt] = __builtin_amdgcn_mfma_f32_16x16x32_bf16(af, hb.s, aacc[tt], 0, 0, 0);
        }
    }
    ushort* dst = isOrig ? (A1bf + (size_t)r * 256) : (A2bf + (size_t)(r - 256) * 256);
#pragma unroll
    for (int tt = 0; tt < 16; ++tt) {
        int tb = tt * 16 + q * 4;
        uint2 pv;
        pv.x = (unsigned)f2bf(aacc[tt][0]) | ((unsigned)f2bf(aacc[tt][1]) << 16);
        pv.y = (unsigned)f2bf(aacc[tt][2]) | ((unsigned)f2bf(aacc[tt][3]) << 16);
        *(uint2*)(dst + tb) = pv;
    }
}

// ---------------- fused sim + top5 ----------------
__global__ __launch_bounds__(256) void simtop_kernel(const float* __restrict__ fo,
                                                     const float* __restrict__ fr,
                                                     const float* __restrict__ rnorm,
                                                     const float* __restrict__ fT,
                                                     int* __restrict__ top5) {
    int b = blockIdx.x;
    int pass = b >> 7, pair = b & 127;
    int i0 = pair * 2, i1 = i0 + 1;
    const float* f = pass ? fr : fo;
    const float* rn = rnorm + pass * 256;
    __shared__ float2 fs2[512];
    __shared__ float candV[4][2][5];
    __shared__ int candI[4][2][5];
    int t = threadIdx.x;
    const float* f0 = f + (size_t)i0 * 512;
    const float* f1 = f + (size_t)i1 * 512;
    fs2[t] = make_float2(f0[t], f1[t]);
    fs2[t + 256] = make_float2(f0[t + 256], f1[t + 256]);
    __syncthreads();
    int j = t;
    const float* col = fT + (size_t)pass * 131072 + j;
    float x0 = 0.f, x1 = 0.f, y0 = 0.f, y1 = 0.f, z0 = 0.f, z1 = 0.f, u0 = 0.f, u1 = 0.f;
#pragma unroll 8
    for (int k = 0; k < 128; ++k) {
        float v0 = col[(size_t)k * 256];
        float v1 = col[(size_t)(k + 128) * 256];
        float v2 = col[(size_t)(k + 256) * 256];
        float v3 = col[(size_t)(k + 384) * 256];
        float2 g0 = fs2[k], g1 = fs2[k + 128], g2 = fs2[k + 256], g3 = fs2[k + 384];
        x0 += g0.x * v0; x1 += g0.y * v0;
        y0 += g1.x * v1; y1 += g1.y * v1;
        z0 += g2.x * v2; z1 += g2.y * v2;
        u0 += g3.x * v3; u1 += g3.y * v3;
    }
    float a0 = ((x0 + y0) + (z0 + u0)) * rn[j];
    float a1 = ((x1 + y1) + (z1 + u1)) * rn[j];
    if (j == i0) a0 = -INFINITY;
    if (j == i1) a1 = -INFINITY;
    int w = t >> 6, lane = t & 63;
    for (int sel = 0; sel < 2; ++sel) {
        float v2 = sel ? a1 : a0;
        int idx = j;
        for (int r = 0; r < 5; ++r) {
            float m = v2;
            int mi = idx;
#pragma unroll
            for (int off = 32; off > 0; off >>= 1) {
                float om = __shfl_xor(m, off);
                int omi = __shfl_xor(mi, off);
                if (om > m || (om == m && omi < mi)) { m = om; mi = omi; }
            }
            if (lane == 0) { candV[w][sel][r] = m; candI[w][sel][r] = mi; }
            if (idx == mi) v2 = -INFINITY;
        }
    }
    __syncthreads();
    if (w < 2) {
        float v = -INFINITY;
        int ix = 0x7fffffff;
        if (lane < 20) { v = candV[lane / 5][w][lane % 5]; ix = candI[lane / 5][w][lane % 5]; }
        int iSel = w ? i1 : i0;
        for (int r = 0; r < 5; ++r) {
            float m = v;
            int mi = ix;
#pragma unroll
            for (int off = 32; off > 0; off >>= 1) {
                float om = __shfl_xor(m, off);
                int omi = __shfl_xor(mi, off);
                if (om > m || (om == m && omi < mi)) { m = om; mi = omi; }
            }
            if (lane == 0) top5[((size_t)pass * 256 + iSel) * 5 + r] = mi;
            if (ix == mi) v = -INFINITY;
        }
    }
}

// ---------------- energy v4: s=2 strips/wave, no spills ----------------
// grid 512: block = (i, half). Wave w covers j in {jb..jb+15, jb+16..jb+31},
// jb = half*128 + w*32. A = W3^T/W4^T frags from global (L2), B in-register.
__global__ __launch_bounds__(256, 2) void energy_v4(
    const ushort* __restrict__ A1bf, const ushort* __restrict__ A2bf,
    const ushort* __restrict__ ebf,
    const ushort* __restrict__ W3p, const ushort* __restrict__ W4p,
    const float* __restrict__ b3, const float* __restrict__ g3, const float* __restrict__ be3,
    const float* __restrict__ b4, const float* __restrict__ W5, const float* __restrict__ b5,
    ushort* __restrict__ E)
{
    int blk = blockIdx.x;
    int i = blk >> 1;
    int half = blk & 1;
    int t = threadIdx.x;
    int w = t >> 6, lane = t & 63, q = lane >> 4, n = lane & 15;
    int jb = half * 128 + w * 32;
    __shared__ float combS[256], g3S[256], be3S[256], b4S[128], w5S[128];
    combS[t] = bf2f(A1bf[(size_t)i * 256 + t]) + b3[t];
    g3S[t] = g3[t];
    be3S[t] = be3[t];
    if (t < 128) { b4S[t] = b4[t]; w5S[t] = W5[t]; }
    __syncthreads();

    const ushort* e1p = ebf + (size_t)i * 256;
    const ushort* e2p = ebf + 65536;

    f32x4 acc[2][16];
#pragma unroll
    for (int s = 0; s < 2; ++s)
#pragma unroll
        for (int tt = 0; tt < 16; ++tt) acc[s][tt] = (f32x4){0.f, 0.f, 0.f, 0.f};

    for (int kk = 0; kk < 8; ++kk) {
        int kbase = kk * 32 + q * 8;
        U8 e1v;
        e1v.v = *(const u32x4*)(e1p + kbase);
        float e1f[8];
#pragma unroll
        for (int x = 0; x < 4; ++x) {
            e1f[2 * x] = bflo(e1v.u[x]);
            e1f[2 * x + 1] = bfhi(e1v.u[x]);
        }
        short8 bfrag[2];
#pragma unroll
        for (int s = 0; s < 2; ++s) {
            U8 e2v;
            e2v.v = *(const u32x4*)(e2p + (size_t)(jb + s * 16 + n) * 256 + kbase);
            U8 bb;
#pragma unroll
            for (int x = 0; x < 4; ++x) {
                float p0 = bflo(e2v.u[x]) * e1f[2 * x];
                float p1 = bfhi(e2v.u[x]) * e1f[2 * x + 1];
                bb.u[x] = (unsigned)f2bf(p0) | ((unsigned)f2bf(p1) << 16);
            }
            bfrag[s] = bb.s;
        }
        const ushort* wp = W3p + ((size_t)(kk * 16) * 64 + lane) * 8;
#pragma unroll
        for (int tt = 0; tt < 16; ++tt) {
            short8 af = *(const short8*)(wp + (size_t)tt * 512);
            acc[0][tt] = __builtin_amdgcn_mfma_f32_16x16x32_bf16(af, bfrag[0], acc[0][tt], 0, 0, 0);
            acc[1][tt] = __builtin_amdgcn_mfma_f32_16x16x32_bf16(af, bfrag[1], acc[1][tt], 0, 0, 0);
        }
    }

    uint2 pk[2][16];
    float b5v = b5[0];
#pragma unroll
    for (int s = 0; s < 2; ++s) {
        int j = jb + s * 16 + n;
        float s1 = 0.f, s2 = 0.f;
#pragma unroll
        for (int tt = 0; tt < 16; ++tt) {
            int tb = tt * 16 + q * 4;
            float4 cb = *(const float4*)(combS + tb);
            uint2 a2u = *(const uint2*)(A2bf + (size_t)j * 256 + tb);
            float a0 = bflo(a2u.x), a1f = bfhi(a2u.x), a2f = bflo(a2u.y), a3f = bfhi(a2u.y);
            float v0 = acc[s][tt][0] + cb.x + a0;
            float v1 = acc[s][tt][1] + cb.y + a1f;
            float v2 = acc[s][tt][2] + cb.z + a2f;
            float v3 = acc[s][tt][3] + cb.w + a3f;
            acc[s][tt][0] = v0; acc[s][tt][1] = v1; acc[s][tt][2] = v2; acc[s][tt][3] = v3;
            s1 += v0 + v1 + v2 + v3;
            s2 += v0 * v0 + v1 * v1 + v2 * v2 + v3 * v3;
        }
        s1 += __shfl_xor(s1, 16); s1 += __shfl_xor(s1, 32);
        s2 += __shfl_xor(s2, 16); s2 += __shfl_xor(s2, 32);
        float mean = s1 * (1.f / 256.f);
        float var = s2 * (1.f / 256.f) - mean * mean;
        float rstd = rsqrtf(var + 1e-5f);
#pragma unroll
        for (int tt = 0; tt < 16; ++tt) {
            int tb = tt * 16 + q * 4;
            float4 gg = *(const float4*)(g3S + tb);
            float4 be = *(const float4*)(be3S + tb);
            float h0 = fmaxf((acc[s][tt][0] - mean) * rstd * gg.x + be.x, 0.f);
            float h1 = fmaxf((acc[s][tt][1] - mean) * rstd * gg.y + be.y, 0.f);
            float h2 = fmaxf((acc[s][tt][2] - mean) * rstd * gg.z + be.z, 0.f);
            float h3 = fmaxf((acc[s][tt][3] - mean) * rstd * gg.w + be.w, 0.f);
            pk[s][tt].x = (unsigned)f2bf(h0) | ((unsigned)f2bf(h1) << 16);
            pk[s][tt].y = (unsigned)f2bf(h2) | ((unsigned)f2bf(h3) << 16);
        }
    }

    f32x4 gacc[2][8];
#pragma unroll
    for (int s = 0; s < 2; ++s)
#pragma unroll
        for (int nt = 0; nt < 8; ++nt) gacc[s][nt] = (f32x4){0.f, 0.f, 0.f, 0.f};

    int qh = (q >> 1) & 1;
    int src0 = ((q & 1) * 2) * 16 + n;
    int src1 = src0 + 16;
#pragma unroll
    for (int kk = 0; kk < 8; ++kk) {
        const ushort* wp = W4p + ((size_t)(kk * 8) * 64 + lane) * 8;
#pragma unroll
        for (int s = 0; s < 2; ++s) {
            uint2 lo2 = pk[s][kk * 2], hi2 = pk[s][kk * 2 + 1];
            unsigned a0 = (unsigned)__shfl((int)lo2.x, src0);
            unsigned a1 = (unsigned)__shfl((int)lo2.y, src0);
            unsigned b0 = (unsigned)__shfl((int)hi2.x, src0);
            unsigned b1 = (unsigned)__shfl((int)hi2.y, src0);
            unsigned c0 = (unsigned)__shfl((int)lo2.x, src1);
            unsigned c1 = (unsigned)__shfl((int)lo2.y, src1);
            unsigned d0 = (unsigned)__shfl((int)hi2.x, src1);
            unsigned d1 = (unsigned)__shfl((int)hi2.y, src1);
            U8 hb;
            hb.u[0] = qh ? b0 : a0;
            hb.u[1] = qh ? b1 : a1;
            hb.u[2] = qh ? d0 : c0;
            hb.u[3] = qh ? d1 : c1;
#pragma unroll
            for (int nt = 0; nt < 8; ++nt) {
                short8 wa = *(const short8*)(wp + (size_t)nt * 512);
                gacc[s][nt] = __builtin_amdgcn_mfma_f32_16x16x32_bf16(wa, hb.s, gacc[s][nt], 0, 0, 0);
            }
        }
    }

#pragma unroll
    for (int s = 0; s < 2; ++s) {
        float ep = 0.f;
#pragma unroll
        for (int nt = 0; nt < 8; ++nt) {
            int nb = nt * 16 + q * 4;
            float4 b4v = *(const float4*)(b4S + nb);
            float4 w5v = *(const float4*)(w5S + nb);
            ep += fmaxf(gacc[s][nt][0] + b4v.x, 0.f) * w5v.x;
            ep += fmaxf(gacc[s][nt][1] + b4v.y, 0.f) * w5v.y;
            ep += fmaxf(gacc[s][nt][2] + b4v.z, 0.f) * w5v.z;
            ep += fmaxf(gacc[s][nt][3] + b4v.w, 0.f) * w5v.w;
        }
        ep += __shfl_xor(ep, 16);
        ep += __shfl_xor(ep, 32);
        if (q == 0) E[(size_t)i * 256 + jb + s * 16 + n] = f2bf(ep + b5v);
    }
}

// ---------------- margin + jaccard ----------------
__global__ void margin_jac_kernel(const ushort* __restrict__ E, const int* __restrict__ top5,
                                  float* slAcc, float* jacOut) {
    __shared__ float red[4];
    int b = blockIdx.x, t = threadIdx.x;
    if (b < 256) {
        float diag = bf2f(E[(size_t)b * 256 + b]);
        float l = (t == b) ? 0.f : fmaxf(1.f + bf2f(E[(size_t)b * 256 + t]) - diag, 0.f);
        float tot = block_sum256(l, red);
        if (t == 0) atomicAdd(slAcc, tot);
    } else {
        int O[5], R[5];
#pragma unroll
        for (int r = 0; r < 5; ++r) {
            O[r] = top5[t * 5 + r];
            R[r] = top5[(256 + t) * 5 + r];
        }
        int inter = 0;
#pragma unroll
        for (int a = 0; a < 5; ++a)
#pragma unroll
            for (int bq = 0; bq < 5; ++bq) inter += (O[a] == R[bq]);
        float fi2 = (float)inter;
        float jac = fi2 / (10.f - fi2 + 1e-8f);
        float s = block_sum256(jac, red);
        if (t == 0) jacOut[0] = s;
    }
}

// ---------------- finalize ----------------
__global__ void finalize_kernel(const float* wsf, const int* h1, const int* h2, float* out) {
    __shared__ float red[4];
    int t = threadIdx.x;
    float p1 = (float)h1[t] / 4194304.f;
    float p2 = (float)h2[t] / 2097152.f;
    float s1 = block_sum256(-p1 * log2f(p1 + 1e-8f), red);
    float s2 = block_sum256(-p2 * log2f(p2 + 1e-8f), red);
    if (t == 0) {
        float recon = wsf[0] / 3145728.f;
        float sp = 0.5f * (wsf[1] / 4194304.f + wsf[2] / 2097152.f);
        float en = 0.5f * (s1 + s2);
        float compress = sp + 0.1f * en;
        float sl = wsf[5] / (256.f * 255.f);
        float nl = 1.f - wsf[6] / 256.f;
        float energy = sl + 0.3f * nl;
        float total = recon + 0.01f * compress + 0.1f * energy;
        out[0] = total;
        out[1] = recon;
        out[2] = energy;
        out[3] = compress;
    }
}

// ---------------- launch ----------------
extern "C" void kernel_launch(void* const* d_in, const int* in_sizes, int n_in,
                              void* d_out, int out_size, void* d_ws, size_t ws_size,
                              hipStream_t stream) {
    const float* outputs = (const float*)d_in[0];
    const float* images  = (const float*)d_in[1];
    const float* f_orig  = (const float*)d_in[2];
    const float* f_recon = (const float*)d_in[3];
    const float* cf1 = (const float*)d_in[4];
    const float* cf2 = (const float*)d_in[5];
    const float* W1 = (const float*)d_in[6];
    const float* b1 = (const float*)d_in[7];
    const float* g1 = (const float*)d_in[8];
    const float* be1 = (const float*)d_in[9];
    const float* W2 = (const float*)d_in[10];
    const float* b2 = (const float*)d_in[11];
    const float* W3 = (const float*)d_in[12];
    const float* b3 = (const float*)d_in[13];
    const float* g3 = (const float*)d_in[14];
    const float* be3 = (const float*)d_in[15];
    const float* W4 = (const float*)d_in[16];
    const float* b4 = (const float*)d_in[17];
    const float* W5 = (const float*)d_in[18];
    const float* b5 = (const float*)d_in[19];

    float* wsf = (float*)d_ws;
    unsigned* wsu = (unsigned*)d_ws;
    int* wsi = (int*)d_ws;
    float* out = (float*)d_out;

    float* rnorm = wsf + 528;
    ushort* A1bf = (ushort*)(wsf + 1040);
    ushort* A2bf = (ushort*)(wsf + 33808);
    ushort* ebf  = (ushort*)(wsf + 66576);
    ushort* Ebf  = (ushort*)(wsf + 132112);
    ushort* W3cpk = (ushort*)(wsf + 164880);
    ushort* W4pk  = (ushort*)(wsf + 197648);
    ushort* W1pk  = (ushort*)(wsf + 214032);
    ushort* W2pk  = (ushort*)(wsf + 279568);
    ushort* W3apk = (ushort*)(wsf + 312336);
    ushort* W3bpk = (ushort*)(wsf + 345104);
    float* fT = wsf + 377872;
    int* top5 = wsi + 640016;

    hipLaunchKernelGGL(init_kernel, dim3(1), dim3(256), 0, stream, wsf, wsu, wsi);
    hipLaunchKernelGGL(mega_kernel, dim3(2384), dim3(256), 0, stream,
                       (const float4*)outputs, (const float4*)images,
                       (const float4*)cf1, (const float4*)cf2,
                       f_orig, f_recon, W1, W2, W3, W4,
                       wsf, wsu, rnorm, fT, W3cpk, W4pk, W1pk, W2pk, W3apk, W3bpk);
    hipLaunchKernelGGL(hist_kernel, dim3(1024), dim3(256), 0, stream,
                       (const float4*)cf1, (const float4*)cf2, wsu, wsi);
    hipLaunchKernelGGL(encoder_mfma, dim3(8), dim3(256), 0, stream,
                       f_orig, f_recon, W1pk, W2pk, W3apk, W3bpk,
                       b1, g1, be1, b2, ebf, A1bf, A2bf);
    hipLaunchKernelGGL(simtop_kernel, dim3(256), dim3(256), 0, stream,
                       f_orig, f_recon, rnorm, fT, top5);
    hipLaunchKernelGGL(energy_v4, dim3(512), dim3(256), 0, stream,
                       A1bf, A2bf, ebf, W3cpk, W4pk, b3, g3, be3, b4, W5, b5, Ebf);
    hipLaunchKernelGGL(margin_jac_kernel, dim3(257), dim3(256), 0, stream,
                       Ebf, top5, wsf + 5, wsf + 6);
    hipLaunchKernelGGL(finalize_kernel, dim3(1), dim3(256), 0, stream,
                       wsf, wsi + 16, wsi + 272, out);
}

// Round 7
// 277.751 us; speedup vs baseline: 1.4894x; 1.2351x over previous
//
#include <hip/hip_runtime.h>
#include <math.h>

typedef __attribute__((ext_vector_type(8))) short short8;
typedef __attribute__((ext_vector_type(4))) float f32x4;
typedef __attribute__((ext_vector_type(4))) unsigned int u32x4;

union U8 { unsigned int u[4]; short8 s; u32x4 v; };

// ---------------- helpers ----------------

__device__ __forceinline__ float wave_sum(float v) {
#pragma unroll
    for (int o = 32; o > 0; o >>= 1) v += __shfl_down(v, o);
    return v;
}

__device__ __forceinline__ float block_sum256(float v, float* red) {
    v = wave_sum(v);
    int t = threadIdx.x;
    if ((t & 63) == 0) red[t >> 6] = v;
    __syncthreads();
    float r = red[0] + red[1] + red[2] + red[3];
    __syncthreads();
    return r;
}

__device__ __forceinline__ unsigned fenc(float f) {
    unsigned u = __float_as_uint(f);
    return (u & 0x80000000u) ? ~u : (u | 0x80000000u);
}
__device__ __forceinline__ float fdec(unsigned u) {
    return (u & 0x80000000u) ? __uint_as_float(u & 0x7fffffffu) : __uint_as_float(~u);
}

__device__ __forceinline__ ushort f2bf(float f) {
    unsigned u = __float_as_uint(f);
    unsigned r = (u + 0x7fffu + ((u >> 16) & 1u)) >> 16;
    return (ushort)r;
}
__device__ __forceinline__ float bflo(unsigned u) { return __uint_as_float(u << 16); }
__device__ __forceinline__ float bfhi(unsigned u) { return __uint_as_float(u & 0xffff0000u); }
__device__ __forceinline__ float bf2f(ushort u) { return __uint_as_float((unsigned)u << 16); }

// ---------------- ws float layout ----------------
// 0..527 scalars + hists (ints)
// 528 rnorm[512] -> 1040
// 1040 A1bf (65536 bf16) -> 33808
// 33808 A2bf (65536 bf16) -> 66576
// 66576 ebf (131072 bf16) -> 132112
// 132112 Ebf (65536 bf16) -> 164880
// 164880 W3cpk -> 197648, 197648 W4pk -> 214032
// 214032 W1pk -> 279568, 279568 W2pk -> 312336
// 312336 W3apk -> 345104, 345104 W3bpk -> 377872
// 377872 fT fp32[262144] -> 640016
// 640016 top5 int[2560] -> 642576

__global__ void init_kernel(float* wsf, unsigned* wsu, int* wsi) {
    int t = threadIdx.x;
    if (t < 7) wsf[t] = 0.f;
    if (t == 7 || t == 9) wsu[t] = 0xFFFFFFFFu;
    if (t == 8 || t == 10) wsu[t] = 0u;
    wsi[16 + t] = 0;
    wsi[272 + t] = 0;
}

// pack a [K x 256] fp32 matrix into bf16 A-fragment order
__device__ __forceinline__ void pack256(const float* __restrict__ src, ushort* __restrict__ dst, int s) {
    int lane = s & 63;
    int tt = (s >> 6) & 15;
    int kk = s >> 10;
    int qq = lane >> 4, nn = lane & 15;
    int tcol = tt * 16 + nn;
    short8 v;
#pragma unroll
    for (int jj = 0; jj < 8; ++jj) {
        int k = kk * 32 + qq * 8 + jj;
        v[jj] = (short)f2bf(src[(size_t)k * 256 + tcol]);
    }
    *(short8*)(dst + (size_t)s * 8) = v;
}

__device__ __forceinline__ void pack128(const float* __restrict__ src, ushort* __restrict__ dst, int s) {
    int lane = s & 63;
    int tt = (s >> 6) & 7;
    int kk = s >> 9;
    int qq = lane >> 4, nn = lane & 15;
    int ncol = tt * 16 + nn;
    short8 v;
#pragma unroll
    for (int jj = 0; jj < 8; ++jj) {
        int k = kk * 32 + qq * 8 + jj;
        v[jj] = (short)f2bf(src[(size_t)k * 128 + ncol]);
    }
    *(short8*)(dst + (size_t)s * 8) = v;
}

// ---------------- mega: stats + transpose + packs ----------------
__global__ __launch_bounds__(256) void mega_kernel(
    const float4* __restrict__ o, const float4* __restrict__ im,
    const float4* __restrict__ cf1, const float4* __restrict__ cf2,
    const float* __restrict__ fo, const float* __restrict__ fr,
    const float* __restrict__ W1, const float* __restrict__ W2,
    const float* __restrict__ W3, const float* __restrict__ W4,
    float* wsf, unsigned* wsu, float* rnorm, float* fT,
    ushort* __restrict__ W3cpk, ushort* __restrict__ W4pk,
    ushort* __restrict__ W1pk, ushort* __restrict__ W2pk,
    ushort* __restrict__ W3apk, ushort* __restrict__ W3bpk) {
    __shared__ float smem[64 * 33];
    float* red = smem;
    int b = blockIdx.x, t = threadIdx.x;
    if (b < 2048) {
        if (b < 512) {
            int base = b * 1536 + t;
            float4 av[6], cv[6];
#pragma unroll
            for (int u = 0; u < 6; ++u) { av[u] = o[base + u * 256]; cv[u] = im[base + u * 256]; }
            float s0 = 0.f, s1 = 0.f;
#pragma unroll
            for (int u = 0; u < 6; ++u) {
                float dx = av[u].x - cv[u].x, dy = av[u].y - cv[u].y;
                float dz = av[u].z - cv[u].z, dw = av[u].w - cv[u].w;
                if (u & 1) s1 += dx * dx + dy * dy + dz * dz + dw * dw;
                else s0 += dx * dx + dy * dy + dz * dz + dw * dw;
            }
            float tot = block_sum256(s0 + s1, red);
            if (t == 0) atomicAdd(wsf + 0, tot);
        } else if (b < 1536) {
            int which = (b < 1024) ? 0 : 1;
            const float4* x = which ? cf2 : cf1;
            int niter = which ? 4 : 8;
            int base = which ? ((b - 1024) * 1024 + t) : ((b - 512) * 2048 + t);
            float4 v[8];
            for (int u = 0; u < niter; ++u) v[u] = x[base + u * 256];
            float s = 0.f, mn = INFINITY, mx = -INFINITY;
            for (int u = 0; u < niter; ++u) {
                float4 a = v[u];
                s += fabsf(a.x) + fabsf(a.y) + fabsf(a.z) + fabsf(a.w);
                mn = fminf(mn, fminf(fminf(a.x, a.y), fminf(a.z, a.w)));
                mx = fmaxf(mx, fmaxf(fmaxf(a.x, a.y), fmaxf(a.z, a.w)));
            }
            float tot = block_sum256(s, red);
#pragma unroll
            for (int off = 32; off > 0; off >>= 1) {
                mn = fminf(mn, __shfl_down(mn, off));
                mx = fmaxf(mx, __shfl_down(mx, off));
            }
            float* rmn = smem + 8;
            float* rmx = smem + 16;
            if ((t & 63) == 0) { rmn[t >> 6] = mn; rmx[t >> 6] = mx; }
            __syncthreads();
            if (t == 0) {
                atomicAdd(wsf + 1 + which, tot);
                float m1 = fminf(fminf(rmn[0], rmn[1]), fminf(rmn[2], rmn[3]));
                float m2 = fmaxf(fmaxf(rmx[0], rmx[1]), fmaxf(rmx[2], rmx[3]));
                atomicMin(wsu + 7 + which * 2, fenc(m1));
                atomicMax(wsu + 8 + which * 2, fenc(m2));
            }
        } else {
            int r = b - 1536;
            const float4* f = (r < 256) ? ((const float4*)fo + (size_t)r * 128)
                                        : ((const float4*)fr + (size_t)(r - 256) * 128);
            float s = 0.f;
            if (t < 128) {
                float4 a = f[t];
                s = a.x * a.x + a.y * a.y + a.z * a.z + a.w * a.w;
            }
            float tot = block_sum256(s, red);
            if (t == 0) rnorm[r] = 1.0f / sqrtf(tot);
        }
    } else if (b < 2176) {
        int bb = b - 2048;
        int pass = bb >> 6;
        int kt = (bb >> 2) & 15;
        int jt = bb & 3;
        int k0 = kt * 32, j0 = jt * 64;
        const float* f = pass ? fr : fo;
        float (*tile)[33] = (float(*)[33])smem;
        int cl = t & 31, rl = t >> 5;
#pragma unroll
        for (int r = 0; r < 8; ++r) {
            int row = j0 + rl + r * 8;
            tile[rl + r * 8][cl] = f[(size_t)row * 512 + k0 + cl];
        }
        __syncthreads();
        int jl = t & 63, kq = t >> 6;
        float* dst = fT + (size_t)pass * 131072;
#pragma unroll
        for (int c = 0; c < 8; ++c) {
            int kl = kq * 8 + c;
            dst[(size_t)(k0 + kl) * 256 + j0 + jl] = tile[jl][kl];
        }
    } else {
        int pb = b - 2176;
        if (pb < 32) pack256(W3 + 512 * 256, W3cpk, pb * 256 + t);
        else if (pb < 48) pack128(W4, W4pk, (pb - 32) * 256 + t);
        else if (pb < 112) pack256(W1, W1pk, (pb - 48) * 256 + t);
        else if (pb < 144) pack256(W2, W2pk, (pb - 112) * 256 + t);
        else if (pb < 176) pack256(W3, W3apk, (pb - 144) * 256 + t);
        else pack256(W3 + 256 * 256, W3bpk, (pb - 176) * 256 + t);
    }
}

// ---------------- merged histogram ----------------
__global__ __launch_bounds__(256) void hist_kernel(const float4* __restrict__ cf1,
                                                   const float4* __restrict__ cf2,
                                                   const unsigned* wsu, int* wsi) {
    __shared__ int hl[256];
    int b = blockIdx.x, t = threadIdx.x;
    hl[t] = 0;
    __syncthreads();
    int which = (b < 512) ? 0 : 1;
    const float4* x = which ? cf2 : cf1;
    int niter = which ? 4 : 8;
    int base = which ? ((b - 512) * 1024 + t) : (b * 2048 + t);
    int* hist = wsi + (which ? 272 : 16);
    float mn = fdec(wsu[7 + which * 2]), mx = fdec(wsu[8 + which * 2]);
    float inv = 256.f / (mx - mn + 1e-8f);
    float4 v[8];
    for (int u = 0; u < niter; ++u) v[u] = x[base + u * 256];
    for (int u = 0; u < niter; ++u) {
        float4 a = v[u];
        int b0i = min(max((int)floorf((a.x - mn) * inv), 0), 255);
        int b1i = min(max((int)floorf((a.y - mn) * inv), 0), 255);
        int b2i = min(max((int)floorf((a.z - mn) * inv), 0), 255);
        int b3i = min(max((int)floorf((a.w - mn) * inv), 0), 255);
        atomicAdd(&hl[b0i], 1);
        atomicAdd(&hl[b1i], 1);
        atomicAdd(&hl[b2i], 1);
        atomicAdd(&hl[b3i], 1);
    }
    __syncthreads();
    if (hl[t]) atomicAdd(&hist[t], hl[t]);
}

// ---------------- encoder via MFMA, one wave per block, reg double-buffer ----------------
// grid 32 x 64 threads. Wave handles rows blk*16 + n (n = lane&15).
__global__ __launch_bounds__(64, 1) void encoder_mfma(
    const float* __restrict__ fo, const float* __restrict__ fr,
    const ushort* __restrict__ W1p, const ushort* __restrict__ W2p,
    const ushort* __restrict__ W3ap, const ushort* __restrict__ W3bp,
    const float* __restrict__ b1, const float* __restrict__ g1,
    const float* __restrict__ be1, const float* __restrict__ b2,
    ushort* __restrict__ ebf, ushort* __restrict__ A1bf, ushort* __restrict__ A2bf)
{
    int lane = threadIdx.x & 63;
    int q = lane >> 4, n = lane & 15;
    int r = blockIdx.x * 16 + n;
    bool isOrig = (r < 256);
    const float* f = isOrig ? (fo + (size_t)r * 512) : (fr + (size_t)(r - 256) * 512);

    // ----- layer 1: X @ W1, double-buffered weight fragments -----
    f32x4 acc[16];
#pragma unroll
    for (int tt = 0; tt < 16; ++tt) acc[tt] = (f32x4){0.f, 0.f, 0.f, 0.f};
    short8 wA[16], wB[16];
    {
        const ushort* wp0 = W1p + (size_t)lane * 8;
#pragma unroll
        for (int tt = 0; tt < 16; ++tt) wA[tt] = *(const short8*)(wp0 + (size_t)tt * 512);
    }
#pragma unroll
    for (int kk = 0; kk < 16; ++kk) {
        const short8* cur = (kk & 1) ? wB : wA;
        short8* nxt = (kk & 1) ? wA : wB;
        if (kk < 15) {
            const ushort* wpn = W1p + ((size_t)((kk + 1) * 1024 + lane)) * 8;
#pragma unroll
            for (int tt = 0; tt < 16; ++tt) nxt[tt] = *(const short8*)(wpn + (size_t)tt * 512);
        }
        int kb = kk * 32 + q * 8;
        float4 fa = *(const float4*)(f + kb);
        float4 fb = *(const float4*)(f + kb + 4);
        U8 bb;
        bb.u[0] = (unsigned)f2bf(fa.x) | ((unsigned)f2bf(fa.y) << 16);
        bb.u[1] = (unsigned)f2bf(fa.z) | ((unsigned)f2bf(fa.w) << 16);
        bb.u[2] = (unsigned)f2bf(fb.x) | ((unsigned)f2bf(fb.y) << 16);
        bb.u[3] = (unsigned)f2bf(fb.z) | ((unsigned)f2bf(fb.w) << 16);
#pragma unroll
        for (int tt = 0; tt < 16; ++tt)
            acc[tt] = __builtin_amdgcn_mfma_f32_16x16x32_bf16(cur[tt], bb.s, acc[tt], 0, 0, 0);
    }
    float s1 = 0.f, s2 = 0.f;
#pragma unroll
    for (int tt = 0; tt < 16; ++tt) {
        int tb = tt * 16 + q * 4;
        float4 bv = *(const float4*)(b1 + tb);
        float v0 = acc[tt][0] + bv.x, v1 = acc[tt][1] + bv.y;
        float v2 = acc[tt][2] + bv.z, v3 = acc[tt][3] + bv.w;
        acc[tt][0] = v0; acc[tt][1] = v1; acc[tt][2] = v2; acc[tt][3] = v3;
        s1 += v0 + v1 + v2 + v3;
        s2 += v0 * v0 + v1 * v1 + v2 * v2 + v3 * v3;
    }
    s1 += __shfl_xor(s1, 16); s1 += __shfl_xor(s1, 32);
    s2 += __shfl_xor(s2, 16); s2 += __shfl_xor(s2, 32);
    float mean = s1 * (1.f / 256.f);
    float var = s2 * (1.f / 256.f) - mean * mean;
    float rstd = rsqrtf(var + 1e-5f);
    uint2 pk[16];
#pragma unroll
    for (int tt = 0; tt < 16; ++tt) {
        int tb = tt * 16 + q * 4;
        float4 gg = *(const float4*)(g1 + tb);
        float4 be = *(const float4*)(be1 + tb);
        float h0 = fmaxf((acc[tt][0] - mean) * rstd * gg.x + be.x, 0.f);
        float h1 = fmaxf((acc[tt][1] - mean) * rstd * gg.y + be.y, 0.f);
        float h2 = fmaxf((acc[tt][2] - mean) * rstd * gg.z + be.z, 0.f);
        float h3 = fmaxf((acc[tt][3] - mean) * rstd * gg.w + be.w, 0.f);
        pk[tt].x = (unsigned)f2bf(h0) | ((unsigned)f2bf(h1) << 16);
        pk[tt].y = (unsigned)f2bf(h2) | ((unsigned)f2bf(h3) << 16);
    }

    int qh = (q >> 1) & 1;
    int src0 = ((q & 1) * 2) * 16 + n;
    int src1 = src0 + 16;

    // ----- layer 2: H @ W2, double-buffered -----
    f32x4 eacc[16];
#pragma unroll
    for (int tt = 0; tt < 16; ++tt) eacc[tt] = (f32x4){0.f, 0.f, 0.f, 0.f};
    {
        const ushort* wp0 = W2p + (size_t)lane * 8;
#pragma unroll
        for (int tt = 0; tt < 16; ++tt) wA[tt] = *(const short8*)(wp0 + (size_t)tt * 512);
    }
#pragma unroll
    for (int kk = 0; kk < 8; ++kk) {
        const short8* cur = (kk & 1) ? wB : wA;
        short8* nxt = (kk & 1) ? wA : wB;
        if (kk < 7) {
            const ushort* wpn = W2p + ((size_t)((kk + 1) * 1024 + lane)) * 8;
#pragma unroll
            for (int tt = 0; tt < 16; ++tt) nxt[tt] = *(const short8*)(wpn + (size_t)tt * 512);
        }
        uint2 lo2 = pk[kk * 2], hi2 = pk[kk * 2 + 1];
        unsigned a0 = (unsigned)__shfl((int)lo2.x, src0);
        unsigned a1 = (unsigned)__shfl((int)lo2.y, src0);
        unsigned b0 = (unsigned)__shfl((int)hi2.x, src0);
        unsigned b1v = (unsigned)__shfl((int)hi2.y, src0);
        unsigned c0 = (unsigned)__shfl((int)lo2.x, src1);
        unsigned c1 = (unsigned)__shfl((int)lo2.y, src1);
        unsigned d0 = (unsigned)__shfl((int)hi2.x, src1);
        unsigned d1 = (unsigned)__shfl((int)hi2.y, src1);
        U8 hb;
        hb.u[0] = qh ? b0 : a0;
        hb.u[1] = qh ? b1v : a1;
        hb.u[2] = qh ? d0 : c0;
        hb.u[3] = qh ? d1 : c1;
#pragma unroll
        for (int tt = 0; tt < 16; ++tt)
            eacc[tt] = __builtin_amdgcn_mfma_f32_16x16x32_bf16(cur[tt], hb.s, eacc[tt], 0, 0, 0);
    }
    uint2 epk[16];
#pragma unroll
    for (int tt = 0; tt < 16; ++tt) {
        int tb = tt * 16 + q * 4;
        float4 bv = *(const float4*)(b2 + tb);
        float e0 = eacc[tt][0] + bv.x, e1 = eacc[tt][1] + bv.y;
        float e2 = eacc[tt][2] + bv.z, e3 = eacc[tt][3] + bv.w;
        epk[tt].x = (unsigned)f2bf(e0) | ((unsigned)f2bf(e1) << 16);
        epk[tt].y = (unsigned)f2bf(e2) | ((unsigned)f2bf(e3) << 16);
        *(uint2*)(ebf + (size_t)r * 256 + tb) = epk[tt];
    }

    // ----- layer 3: e @ W3a|W3b, double-buffered -----
    const ushort* W3x = isOrig ? W3ap : W3bp;
    f32x4 aacc[16];
#pragma unroll
    for (int tt = 0; tt < 16; ++tt) aacc[tt] = (f32x4){0.f, 0.f, 0.f, 0.f};
    {
        const ushort* wp0 = W3x + (size_t)lane * 8;
#pragma unroll
        for (int tt = 0; tt < 16; ++tt) wA[tt] = *(const short8*)(wp0 + (size_t)tt * 512);
    }
#pragma unroll
    for (int kk = 0; kk < 8; ++kk) {
        const short8* cur = (kk & 1) ? wB : wA;
        short8* nxt = (kk & 1) ? wA : wB;
        if (kk < 7) {
            const ushort* wpn = W3x + ((size_t)((kk + 1) * 1024 + lane)) * 8;
#pragma unroll
            for (int tt = 0; tt < 16; ++tt) nxt[tt] = *(const short8*)(wpn + (size_t)tt * 512);
        }
        uint2 lo2 = epk[kk * 2], hi2 = epk[kk * 2 + 1];
        unsigned a0 = (unsigned)__shfl((int)lo2.x, src0);
        unsigned a1 = (unsigned)__shfl((int)lo2.y, src0);
        unsigned b0 = (unsigned)__shfl((int)hi2.x, src0);
        unsigned b1v = (unsigned)__shfl((int)hi2.y, src0);
        unsigned c0 = (unsigned)__shfl((int)lo2.x, src1);
        unsigned c1 = (unsigned)__shfl((int)lo2.y, src1);
        unsigned d0 = (unsigned)__shfl((int)hi2.x, src1);
        unsigned d1 = (unsigned)__shfl((int)hi2.y, src1);
        U8 hb;
        hb.u[0] = qh ? b0 : a0;
        hb.u[1] = qh ? b1v : a1;
        hb.u[2] = qh ? d0 : c0;
        hb.u[3] = qh ? d1 : c1;
#pragma unroll
        for (int tt = 0; tt < 16; ++tt)
            aacc[tt] = __builtin_amdgcn_mfma_f32_16x16x32_bf16(cur[tt], hb.s, aacc[tt], 0, 0, 0);
    }
    ushort* dst = isOrig ? (A1bf + (size_t)r * 256) : (A2bf + (size_t)(r - 256) * 256);
#pragma unroll
    for (int tt = 0; tt < 16; ++tt) {
        int tb = tt * 16 + q * 4;
        uint2 pv;
        pv.x = (unsigned)f2bf(aacc[tt][0]) | ((unsigned)f2bf(aacc[tt][1]) << 16);
        pv.y = (unsigned)f2bf(aacc[tt][2]) | ((unsigned)f2bf(aacc[tt][3]) << 16);
        *(uint2*)(dst + tb) = pv;
    }
}

// ---------------- fused sim + top5 ----------------
__global__ __launch_bounds__(256) void simtop_kernel(const float* __restrict__ fo,
                                                     const float* __restrict__ fr,
                                                     const float* __restrict__ rnorm,
                                                     const float* __restrict__ fT,
                                                     int* __restrict__ top5) {
    int b = blockIdx.x;
    int pass = b >> 7, pair = b & 127;
    int i0 = pair * 2, i1 = i0 + 1;
    const float* f = pass ? fr : fo;
    const float* rn = rnorm + pass * 256;
    __shared__ float2 fs2[512];
    __shared__ float candV[4][2][5];
    __shared__ int candI[4][2][5];
    int t = threadIdx.x;
    const float* f0 = f + (size_t)i0 * 512;
    const float* f1 = f + (size_t)i1 * 512;
    fs2[t] = make_float2(f0[t], f1[t]);
    fs2[t + 256] = make_float2(f0[t + 256], f1[t + 256]);
    __syncthreads();
    int j = t;
    const float* col = fT + (size_t)pass * 131072 + j;
    float x0 = 0.f, x1 = 0.f, y0 = 0.f, y1 = 0.f, z0 = 0.f, z1 = 0.f, u0 = 0.f, u1 = 0.f;
#pragma unroll 8
    for (int k = 0; k < 128; ++k) {
        float v0 = col[(size_t)k * 256];
        float v1 = col[(size_t)(k + 128) * 256];
        float v2 = col[(size_t)(k + 256) * 256];
        float v3 = col[(size_t)(k + 384) * 256];
        float2 g0 = fs2[k], g1 = fs2[k + 128], g2 = fs2[k + 256], g3 = fs2[k + 384];
        x0 += g0.x * v0; x1 += g0.y * v0;
        y0 += g1.x * v1; y1 += g1.y * v1;
        z0 += g2.x * v2; z1 += g2.y * v2;
        u0 += g3.x * v3; u1 += g3.y * v3;
    }
    float a0 = ((x0 + y0) + (z0 + u0)) * rn[j];
    float a1 = ((x1 + y1) + (z1 + u1)) * rn[j];
    if (j == i0) a0 = -INFINITY;
    if (j == i1) a1 = -INFINITY;
    int w = t >> 6, lane = t & 63;
    for (int sel = 0; sel < 2; ++sel) {
        float v2 = sel ? a1 : a0;
        int idx = j;
        for (int r = 0; r < 5; ++r) {
            float m = v2;
            int mi = idx;
#pragma unroll
            for (int off = 32; off > 0; off >>= 1) {
                float om = __shfl_xor(m, off);
                int omi = __shfl_xor(mi, off);
                if (om > m || (om == m && omi < mi)) { m = om; mi = omi; }
            }
            if (lane == 0) { candV[w][sel][r] = m; candI[w][sel][r] = mi; }
            if (idx == mi) v2 = -INFINITY;
        }
    }
    __syncthreads();
    if (w < 2) {
        float v = -INFINITY;
        int ix = 0x7fffffff;
        if (lane < 20) { v = candV[lane / 5][w][lane % 5]; ix = candI[lane / 5][w][lane % 5]; }
        int iSel = w ? i1 : i0;
        for (int r = 0; r < 5; ++r) {
            float m = v;
            int mi = ix;
#pragma unroll
            for (int off = 32; off > 0; off >>= 1) {
                float om = __shfl_xor(m, off);
                int omi = __shfl_xor(mi, off);
                if (om > m || (om == m && omi < mi)) { m = om; mi = omi; }
            }
            if (lane == 0) top5[((size_t)pass * 256 + iSel) * 5 + r] = mi;
            if (ix == mi) v = -INFINITY;
        }
    }
}

// ---------------- energy v4: s=2 strips/wave, no spills ----------------
__global__ __launch_bounds__(256, 2) void energy_v4(
    const ushort* __restrict__ A1bf, const ushort* __restrict__ A2bf,
    const ushort* __restrict__ ebf,
    const ushort* __restrict__ W3p, const ushort* __restrict__ W4p,
    const float* __restrict__ b3, const float* __restrict__ g3, const float* __restrict__ be3,
    const float* __restrict__ b4, const float* __restrict__ W5, const float* __restrict__ b5,
    ushort* __restrict__ E)
{
    int blk = blockIdx.x;
    int i = blk >> 1;
    int half = blk & 1;
    int t = threadIdx.x;
    int w = t >> 6, lane = t & 63, q = lane >> 4, n = lane & 15;
    int jb = half * 128 + w * 32;
    __shared__ float combS[256], g3S[256], be3S[256], b4S[128], w5S[128];
    combS[t] = bf2f(A1bf[(size_t)i * 256 + t]) + b3[t];
    g3S[t] = g3[t];
    be3S[t] = be3[t];
    if (t < 128) { b4S[t] = b4[t]; w5S[t] = W5[t]; }
    __syncthreads();

    const ushort* e1p = ebf + (size_t)i * 256;
    const ushort* e2p = ebf + 65536;

    f32x4 acc[2][16];
#pragma unroll
    for (int s = 0; s < 2; ++s)
#pragma unroll
        for (int tt = 0; tt < 16; ++tt) acc[s][tt] = (f32x4){0.f, 0.f, 0.f, 0.f};

    for (int kk = 0; kk < 8; ++kk) {
        int kbase = kk * 32 + q * 8;
        U8 e1v;
        e1v.v = *(const u32x4*)(e1p + kbase);
        float e1f[8];
#pragma unroll
        for (int x = 0; x < 4; ++x) {
            e1f[2 * x] = bflo(e1v.u[x]);
            e1f[2 * x + 1] = bfhi(e1v.u[x]);
        }
        short8 bfrag[2];
#pragma unroll
        for (int s = 0; s < 2; ++s) {
            U8 e2v;
            e2v.v = *(const u32x4*)(e2p + (size_t)(jb + s * 16 + n) * 256 + kbase);
            U8 bb;
#pragma unroll
            for (int x = 0; x < 4; ++x) {
                float p0 = bflo(e2v.u[x]) * e1f[2 * x];
                float p1 = bfhi(e2v.u[x]) * e1f[2 * x + 1];
                bb.u[x] = (unsigned)f2bf(p0) | ((unsigned)f2bf(p1) << 16);
            }
            bfrag[s] = bb.s;
        }
        const ushort* wp = W3p + ((size_t)(kk * 16) * 64 + lane) * 8;
#pragma unroll
        for (int tt = 0; tt < 16; ++tt) {
            short8 af = *(const short8*)(wp + (size_t)tt * 512);
            acc[0][tt] = __builtin_amdgcn_mfma_f32_16x16x32_bf16(af, bfrag[0], acc[0][tt], 0, 0, 0);
            acc[1][tt] = __builtin_amdgcn_mfma_f32_16x16x32_bf16(af, bfrag[1], acc[1][tt], 0, 0, 0);
        }
    }

    uint2 pk[2][16];
    float b5v = b5[0];
#pragma unroll
    for (int s = 0; s < 2; ++s) {
        int j = jb + s * 16 + n;
        float s1 = 0.f, s2 = 0.f;
#pragma unroll
        for (int tt = 0; tt < 16; ++tt) {
            int tb = tt * 16 + q * 4;
            float4 cb = *(const float4*)(combS + tb);
            uint2 a2u = *(const uint2*)(A2bf + (size_t)j * 256 + tb);
            float a0 = bflo(a2u.x), a1f = bfhi(a2u.x), a2f = bflo(a2u.y), a3f = bfhi(a2u.y);
            float v0 = acc[s][tt][0] + cb.x + a0;
            float v1 = acc[s][tt][1] + cb.y + a1f;
            float v2 = acc[s][tt][2] + cb.z + a2f;
            float v3 = acc[s][tt][3] + cb.w + a3f;
            acc[s][tt][0] = v0; acc[s][tt][1] = v1; acc[s][tt][2] = v2; acc[s][tt][3] = v3;
            s1 += v0 + v1 + v2 + v3;
            s2 += v0 * v0 + v1 * v1 + v2 * v2 + v3 * v3;
        }
        s1 += __shfl_xor(s1, 16); s1 += __shfl_xor(s1, 32);
        s2 += __shfl_xor(s2, 16); s2 += __shfl_xor(s2, 32);
        float mean = s1 * (1.f / 256.f);
        float var = s2 * (1.f / 256.f) - mean * mean;
        float rstd = rsqrtf(var + 1e-5f);
#pragma unroll
        for (int tt = 0; tt < 16; ++tt) {
            int tb = tt * 16 + q * 4;
            float4 gg = *(const float4*)(g3S + tb);
            float4 be = *(const float4*)(be3S + tb);
            float h0 = fmaxf((acc[s][tt][0] - mean) * rstd * gg.x + be.x, 0.f);
            float h1 = fmaxf((acc[s][tt][1] - mean) * rstd * gg.y + be.y, 0.f);
            float h2 = fmaxf((acc[s][tt][2] - mean) * rstd * gg.z + be.z, 0.f);
            float h3 = fmaxf((acc[s][tt][3] - mean) * rstd * gg.w + be.w, 0.f);
            pk[s][tt].x = (unsigned)f2bf(h0) | ((unsigned)f2bf(h1) << 16);
            pk[s][tt].y = (unsigned)f2bf(h2) | ((unsigned)f2bf(h3) << 16);
        }
    }

    f32x4 gacc[2][8];
#pragma unroll
    for (int s = 0; s < 2; ++s)
#pragma unroll
        for (int nt = 0; nt < 8; ++nt) gacc[s][nt] = (f32x4){0.f, 0.f, 0.f, 0.f};

    int qh = (q >> 1) & 1;
    int src0 = ((q & 1) * 2) * 16 + n;
    int src1 = src0 + 16;
#pragma unroll
    for (int kk = 0; kk < 8; ++kk) {
        const ushort* wp = W4p + ((size_t)(kk * 8) * 64 + lane) * 8;
#pragma unroll
        for (int s = 0; s < 2; ++s) {
            uint2 lo2 = pk[s][kk * 2], hi2 = pk[s][kk * 2 + 1];
            unsigned a0 = (unsigned)__shfl((int)lo2.x, src0);
            unsigned a1 = (unsigned)__shfl((int)lo2.y, src0);
            unsigned b0 = (unsigned)__shfl((int)hi2.x, src0);
            unsigned b1 = (unsigned)__shfl((int)hi2.y, src0);
            unsigned c0 = (unsigned)__shfl((int)lo2.x, src1);
            unsigned c1 = (unsigned)__shfl((int)lo2.y, src1);
            unsigned d0 = (unsigned)__shfl((int)hi2.x, src1);
            unsigned d1 = (unsigned)__shfl((int)hi2.y, src1);
            U8 hb;
            hb.u[0] = qh ? b0 : a0;
            hb.u[1] = qh ? b1 : a1;
            hb.u[2] = qh ? d0 : c0;
            hb.u[3] = qh ? d1 : c1;
#pragma unroll
            for (int nt = 0; nt < 8; ++nt) {
                short8 wa = *(const short8*)(wp + (size_t)nt * 512);
                gacc[s][nt] = __builtin_amdgcn_mfma_f32_16x16x32_bf16(wa, hb.s, gacc[s][nt], 0, 0, 0);
            }
        }
    }

#pragma unroll
    for (int s = 0; s < 2; ++s) {
        float ep = 0.f;
#pragma unroll
        for (int nt = 0; nt < 8; ++nt) {
            int nb = nt * 16 + q * 4;
            float4 b4v = *(const float4*)(b4S + nb);
            float4 w5v = *(const float4*)(w5S + nb);
            ep += fmaxf(gacc[s][nt][0] + b4v.x, 0.f) * w5v.x;
            ep += fmaxf(gacc[s][nt][1] + b4v.y, 0.f) * w5v.y;
            ep += fmaxf(gacc[s][nt][2] + b4v.z, 0.f) * w5v.z;
            ep += fmaxf(gacc[s][nt][3] + b4v.w, 0.f) * w5v.w;
        }
        ep += __shfl_xor(ep, 16);
        ep += __shfl_xor(ep, 32);
        if (q == 0) E[(size_t)i * 256 + jb + s * 16 + n] = f2bf(ep + b5v);
    }
}

// ---------------- margin + jaccard ----------------
__global__ void margin_jac_kernel(const ushort* __restrict__ E, const int* __restrict__ top5,
                                  float* slAcc, float* jacOut) {
    __shared__ float red[4];
    int b = blockIdx.x, t = threadIdx.x;
    if (b < 256) {
        float diag = bf2f(E[(size_t)b * 256 + b]);
        float l = (t == b) ? 0.f : fmaxf(1.f + bf2f(E[(size_t)b * 256 + t]) - diag, 0.f);
        float tot = block_sum256(l, red);
        if (t == 0) atomicAdd(slAcc, tot);
    } else {
        int O[5], R[5];
#pragma unroll
        for (int r = 0; r < 5; ++r) {
            O[r] = top5[t * 5 + r];
            R[r] = top5[(256 + t) * 5 + r];
        }
        int inter = 0;
#pragma unroll
        for (int a = 0; a < 5; ++a)
#pragma unroll
            for (int bq = 0; bq < 5; ++bq) inter += (O[a] == R[bq]);
        float fi2 = (float)inter;
        float jac = fi2 / (10.f - fi2 + 1e-8f);
        float s = block_sum256(jac, red);
        if (t == 0) jacOut[0] = s;
    }
}

// ---------------- finalize ----------------
__global__ void finalize_kernel(const float* wsf, const int* h1, const int* h2, float* out) {
    __shared__ float red[4];
    int t = threadIdx.x;
    float p1 = (float)h1[t] / 4194304.f;
    float p2 = (float)h2[t] / 2097152.f;
    float s1 = block_sum256(-p1 * log2f(p1 + 1e-8f), red);
    float s2 = block_sum256(-p2 * log2f(p2 + 1e-8f), red);
    if (t == 0) {
        float recon = wsf[0] / 3145728.f;
        float sp = 0.5f * (wsf[1] / 4194304.f + wsf[2] / 2097152.f);
        float en = 0.5f * (s1 + s2);
        float compress = sp + 0.1f * en;
        float sl = wsf[5] / (256.f * 255.f);
        float nl = 1.f - wsf[6] / 256.f;
        float energy = sl + 0.3f * nl;
        float total = recon + 0.01f * compress + 0.1f * energy;
        out[0] = total;
        out[1] = recon;
        out[2] = energy;
        out[3] = compress;
    }
}

// ---------------- launch ----------------
extern "C" void kernel_launch(void* const* d_in, const int* in_sizes, int n_in,
                              void* d_out, int out_size, void* d_ws, size_t ws_size,
                              hipStream_t stream) {
    const float* outputs = (const float*)d_in[0];
    const float* images  = (const float*)d_in[1];
    const float* f_orig  = (const float*)d_in[2];
    const float* f_recon = (const float*)d_in[3];
    const float* cf1 = (const float*)d_in[4];
    const float* cf2 = (const float*)d_in[5];
    const float* W1 = (const float*)d_in[6];
    const float* b1 = (const float*)d_in[7];
    const float* g1 = (const float*)d_in[8];
    const float* be1 = (const float*)d_in[9];
    const float* W2 = (const float*)d_in[10];
    const float* b2 = (const float*)d_in[11];
    const float* W3 = (const float*)d_in[12];
    const float* b3 = (const float*)d_in[13];
    const float* g3 = (const float*)d_in[14];
    const float* be3 = (const float*)d_in[15];
    const float* W4 = (const float*)d_in[16];
    const float* b4 = (const float*)d_in[17];
    const float* W5 = (const float*)d_in[18];
    const float* b5 = (const float*)d_in[19];

    float* wsf = (float*)d_ws;
    unsigned* wsu = (unsigned*)d_ws;
    int* wsi = (int*)d_ws;
    float* out = (float*)d_out;

    float* rnorm = wsf + 528;
    ushort* A1bf = (ushort*)(wsf + 1040);
    ushort* A2bf = (ushort*)(wsf + 33808);
    ushort* ebf  = (ushort*)(wsf + 66576);
    ushort* Ebf  = (ushort*)(wsf + 132112);
    ushort* W3cpk = (ushort*)(wsf + 164880);
    ushort* W4pk  = (ushort*)(wsf + 197648);
    ushort* W1pk  = (ushort*)(wsf + 214032);
    ushort* W2pk  = (ushort*)(wsf + 279568);
    ushort* W3apk = (ushort*)(wsf + 312336);
    ushort* W3bpk = (ushort*)(wsf + 345104);
    float* fT = wsf + 377872;
    int* top5 = wsi + 640016;

    hipLaunchKernelGGL(init_kernel, dim3(1), dim3(256), 0, stream, wsf, wsu, wsi);
    hipLaunchKernelGGL(mega_kernel, dim3(2384), dim3(256), 0, stream,
                       (const float4*)outputs, (const float4*)images,
                       (const float4*)cf1, (const float4*)cf2,
                       f_orig, f_recon, W1, W2, W3, W4,
                       wsf, wsu, rnorm, fT, W3cpk, W4pk, W1pk, W2pk, W3apk, W3bpk);
    hipLaunchKernelGGL(hist_kernel, dim3(1024), dim3(256), 0, stream,
                       (const float4*)cf1, (const float4*)cf2, wsu, wsi);
    hipLaunchKernelGGL(encoder_mfma, dim3(32), dim3(64), 0, stream,
                       f_orig, f_recon, W1pk, W2pk, W3apk, W3bpk,
                       b1, g1, be1, b2, ebf, A1bf, A2bf);
    hipLaunchKernelGGL(simtop_kernel, dim3(256), dim3(256), 0, stream,
                       f_orig, f_recon, rnorm, fT, top5);
    hipLaunchKernelGGL(energy_v4, dim3(512), dim3(256), 0, stream,
                       A1bf, A2bf, ebf, W3cpk, W4pk, b3, g3, be3, b4, W5, b5, Ebf);
    hipLaunchKernelGGL(margin_jac_kernel, dim3(257), dim3(256), 0, stream,
                       Ebf, top5, wsf + 5, wsf + 6);
    hipLaunchKernelGGL(finalize_kernel, dim3(1), dim3(256), 0, stream,
                       wsf, wsi + 16, wsi + 272, out);
}